// Round 2
// baseline (10598.830 us; speedup 1.0000x reference)
//
#include <hip/hip_runtime.h>
#include <hip/hip_bf16.h>

typedef __hip_bfloat16 bf16;

#define BN    4
#define HIST  24
#define PRED  12
#define NNODE 10000
#define NEDGE 160000
#define FEAT  31      // IN_DIM-1
#define TSTEPS 36     // HIST+PRED
#define EH    32
#define EOUT  30
#define GOUT  9
#define HID   64

// ---- workspace layout (float offsets) ----
#define IDX_FLAG 4         // 1.0 = inputs are bf16, 0.0 = inputs are f32
#define OFF_W    16
#define W_WE1   0          // 67*32  [i][j]
#define W_BE1   2144       // 32
#define W_WE2T  2176       // 30*32  [k][j] (transposed)
#define W_BE2   3136       // 30
#define W_WN    3166       // 30*9   [k][m]
#define W_BN    3436       // 9
#define W_WIHT  3445       // 192*41 [row][i] (transposed)
#define W_BIH   11317      // 192
#define W_WHHT  11509      // 192*64 [row][i] (transposed)
#define W_BHH   23797      // 192
#define W_WOUT  23989      // 64
#define W_BOUT  24053      // 1
#define W_WM    24054      // 2 wind_mean
#define W_WSD   24056      // 2 wind_std
#define W_TOTAL 24058

#define OFF_XN  24096      // B*N floats (40000)
#define OFF_AGG 64096      // B*N*9 floats (360000)
#define OFF_H   424096     // B*N*64 floats (2560000), in-place updated
// total = 2,984,096 floats = 11.94 MB of ws

__device__ __forceinline__ float cvt(bf16 v)  { return __bfloat162float(v); }
__device__ __forceinline__ float cvt(float v) { return v; }
__device__ __forceinline__ float sigm(float x){ return 1.0f / (1.0f + __expf(-x)); }

// ---- dtype sniff: even bf16 elements of edge_attr are dist in [0.1,1.1] iff bf16 ----
__global__ void k_sniff(float* __restrict__ wsf, const void* __restrict__ ea)
{
    const bf16* p = (const bf16*)ea;
    int lane = threadIdx.x;                   // launched with 64 threads
    float v = __bfloat162float(p[2 * lane]);  // even idx: dist (bf16) vs low-mantissa junk (f32)
    bool ok = (v >= 0.03f) && (v <= 1.3f);
    unsigned long long m = __ballot(ok);
    if (lane == 0) wsf[IDX_FLAG] = (m == ~0ull) ? 1.0f : 0.0f;
}

// ---- convert + transpose all weights -> f32 in ws ----
template<typename T>
__device__ __forceinline__ void weights_body(float* W,
    const T* We1, const T* be1, const T* We2, const T* be2,
    const T* Wn,  const T* bn,  const T* Wih, const T* bih,
    const T* Whh, const T* bhh, const T* Wout, const T* bout,
    const T* wm,  const T* wsd)
{
    int r = blockIdx.x * blockDim.x + threadIdx.x;
    if (r < 2144) { W[W_WE1 + r] = cvt(We1[r]); return; } r -= 2144;
    if (r < 32)   { W[W_BE1 + r] = cvt(be1[r]); return; } r -= 32;
    if (r < 960)  { int k = r / 32, j = r % 32; W[W_WE2T + r] = cvt(We2[j*30 + k]); return; } r -= 960;
    if (r < 30)   { W[W_BE2 + r] = cvt(be2[r]); return; } r -= 30;
    if (r < 270)  { W[W_WN  + r] = cvt(Wn[r]);  return; } r -= 270;
    if (r < 9)    { W[W_BN  + r] = cvt(bn[r]);  return; } r -= 9;
    if (r < 7872) { int row = r / 41, i = r % 41; W[W_WIHT + r] = cvt(Wih[i*192 + row]); return; } r -= 7872;
    if (r < 192)  { W[W_BIH + r] = cvt(bih[r]); return; } r -= 192;
    if (r < 12288){ int row = r / 64, i = r % 64; W[W_WHHT + r] = cvt(Whh[i*192 + row]); return; } r -= 12288;
    if (r < 192)  { W[W_BHH + r] = cvt(bhh[r]); return; } r -= 192;
    if (r < 64)   { W[W_WOUT + r] = cvt(Wout[r]); return; } r -= 64;
    if (r < 1)    { W[W_BOUT] = cvt(bout[0]); return; } r -= 1;
    if (r < 2)    { W[W_WM + r] = cvt(wm[r]); return; } r -= 2;
    if (r < 2)    { W[W_WSD + r] = cvt(wsd[r]); return; }
}

__global__ void k_weights(float* wsf,
    const void* We1, const void* be1, const void* We2, const void* be2,
    const void* Wn,  const void* bn,  const void* Wih, const void* bih,
    const void* Whh, const void* bhh, const void* Wout, const void* bout,
    const void* wm,  const void* wsd)
{
    float* W = wsf + OFF_W;
    if (wsf[IDX_FLAG] > 0.5f)
        weights_body(W, (const bf16*)We1, (const bf16*)be1, (const bf16*)We2, (const bf16*)be2,
                        (const bf16*)Wn,  (const bf16*)bn,  (const bf16*)Wih, (const bf16*)bih,
                        (const bf16*)Whh, (const bf16*)bhh, (const bf16*)Wout, (const bf16*)bout,
                        (const bf16*)wm,  (const bf16*)wsd);
    else
        weights_body(W, (const float*)We1, (const float*)be1, (const float*)We2, (const float*)be2,
                        (const float*)Wn,  (const float*)bn,  (const float*)Wih, (const float*)bih,
                        (const float*)Whh, (const float*)bhh, (const float*)Wout, (const float*)bout,
                        (const float*)wm,  (const float*)wsd);
}

// ---- edge_attr column sums / sumsq (for mean/std ddof=1) ----
template<typename T>
__device__ __forceinline__ void stats_body(float* wsf, const T* ea)
{
    int e = blockIdx.x * 256 + threadIdx.x;   // E = 625*256 exact
    float d = cvt(ea[2*e]), c = cvt(ea[2*e + 1]);
    float v0 = d, v1 = c, v2 = d*d, v3 = c*c;
    #pragma unroll
    for (int o = 32; o > 0; o >>= 1) {
        v0 += __shfl_down(v0, o);
        v1 += __shfl_down(v1, o);
        v2 += __shfl_down(v2, o);
        v3 += __shfl_down(v3, o);
    }
    if ((threadIdx.x & 63) == 0) {
        unsafeAtomicAdd(&wsf[0], v0);
        unsafeAtomicAdd(&wsf[1], v1);
        unsafeAtomicAdd(&wsf[2], v2);
        unsafeAtomicAdd(&wsf[3], v3);
    }
}

__global__ __launch_bounds__(256) void k_stats(float* wsf, const void* ea)
{
    if (wsf[IDX_FLAG] > 0.5f) stats_body(wsf, (const bf16*)ea);
    else                      stats_body(wsf, (const float*)ea);
}

// ---- init xn state from rain_hist[:, HIST-1, :, 0] ----
template<typename T>
__device__ __forceinline__ void init_body(float* wsf, const T* rain)
{
    int g = blockIdx.x * blockDim.x + threadIdx.x;
    if (g >= BN * NNODE) return;
    int b = g / NNODE, n = g % NNODE;
    wsf[OFF_XN + g] = cvt(rain[(b * HIST + (HIST - 1)) * NNODE + n]);
}

__global__ void k_init(float* wsf, const void* rain)
{
    if (wsf[IDX_FLAG] > 0.5f) init_body(wsf, (const bf16*)rain);
    else                      init_body(wsf, (const float*)rain);
}

// ---- edge MLP + scatter (f = e @ Wn, 9-dim atomics) ----
template<typename T>
__device__ __forceinline__ void edge_body(float* wsf, const int* eidx,
                                          const T* ea, const T* feature, int t)
{
    int e = blockIdx.x * 256 + threadIdx.x;   // E exact
    int b = blockIdx.y;
    const float* W = wsf + OFF_W;

    int src = eidx[e], tgt = eidx[NEDGE + e];

    const float invE = 1.0f / (float)NEDGE;
    float s0 = wsf[0], s1 = wsf[1], q0 = wsf[2], q1 = wsf[3];
    float m0 = s0 * invE, m1 = s1 * invE;
    float istd0 = rsqrtf(fmaxf((q0 - s0 * m0) * (1.0f / (NEDGE - 1)), 1e-20f));
    float istd1 = rsqrtf(fmaxf((q1 - s1 * m1) * (1.0f / (NEDGE - 1)), 1e-20f));

    float dist = cvt(ea[2*e]), cdir = cvt(ea[2*e + 1]);
    float ean0 = (dist - m0) * istd0, ean1 = (cdir - m1) * istd1;

    size_t frow = (size_t)(b * TSTEPS + HIST + t) * NNODE;
    const T* fS = feature + (frow + src) * FEAT;
    const T* fT = feature + (frow + tgt) * FEAT;
    float xnS = wsf[OFF_XN + b * NNODE + src];
    float xnT = wsf[OFF_XN + b * NNODE + tgt];

    // wind (src feature dims 29,30 == x dims 30,31)
    float speed = cvt(fS[29]) * W[W_WSD + 0] + W[W_WM + 0];
    float direc = cvt(fS[30]) * W[W_WSD + 1] + W[W_WM + 1];
    float theta = fabsf(cdir - direc);
    float ew = 3.0f * speed * cosf(theta * 22.5f) / dist;
    ew = fmaxf(ew, 0.0f);

    // layer 1: 67 -> 32, i-outer streaming, 32 accumulators
    const float* We1 = W + W_WE1;
    float acc[EH];
    #pragma unroll
    for (int j = 0; j < EH; j++)
        acc[j] = W[W_BE1 + j] + xnS * We1[j] + xnT * We1[32*EH + j]
               + ean0 * We1[64*EH + j] + ean1 * We1[65*EH + j] + ew * We1[66*EH + j];
    for (int i = 0; i < FEAT; i++) {
        float v = cvt(fS[i]);
        const float* wr = We1 + (1 + i) * EH;
        #pragma unroll
        for (int j = 0; j < EH; j++) acc[j] += v * wr[j];
    }
    for (int i = 0; i < FEAT; i++) {
        float v = cvt(fT[i]);
        const float* wr = We1 + (33 + i) * EH;
        #pragma unroll
        for (int j = 0; j < EH; j++) acc[j] += v * wr[j];
    }
    #pragma unroll
    for (int j = 0; j < EH; j++) acc[j] = sigm(acc[j]);

    // layer 2 (32 -> 30 sigmoid) fused with f = e @ Wn (30 -> 9)
    float f9[GOUT];
    #pragma unroll
    for (int m = 0; m < GOUT; m++) f9[m] = 0.0f;
    const float* We2T = W + W_WE2T;
    const float* WnW  = W + W_WN;
    for (int k = 0; k < EOUT; k++) {
        float a = W[W_BE2 + k];
        const float* wr = We2T + k * EH;
        #pragma unroll
        for (int j = 0; j < EH; j++) a += acc[j] * wr[j];
        float ek = sigm(a);
        const float* wn = WnW + k * GOUT;
        #pragma unroll
        for (int m = 0; m < GOUT; m++) f9[m] += ek * wn[m];
    }

    float* aggT = wsf + OFF_AGG + (size_t)(b * NNODE + tgt) * GOUT;
    float* aggS = wsf + OFF_AGG + (size_t)(b * NNODE + src) * GOUT;
    #pragma unroll
    for (int m = 0; m < GOUT; m++) {
        unsafeAtomicAdd(&aggT[m],  f9[m]);
        unsafeAtomicAdd(&aggS[m], -f9[m]);
    }
}

__global__ __launch_bounds__(256) void k_edge(float* wsf, const int* eidx,
                                              const void* ea, const void* feature, int t)
{
    if (wsf[IDX_FLAG] > 0.5f) edge_body(wsf, eidx, (const bf16*)ea, (const bf16*)feature, t);
    else                      edge_body(wsf, eidx, (const float*)ea, (const float*)feature, t);
}

// ---- GRU: block = 64 nodes x 4 waves; wave q does hid chunk [16q,16q+16) ----
// H updated in place: all loads before __syncthreads, all stores after.
template<typename T, typename OT>
__device__ __forceinline__ void gru_body(float* wsf, const T* feature, OT* out, int t)
{
    __shared__ float lpx[4][64];
    int lane = threadIdx.x & 63, q = threadIdx.x >> 6;
    int g = blockIdx.x * 64 + lane;       // B*N = 625*64 exact
    int b = g / NNODE, n = g % NNODE;
    const float* W = wsf + OFF_W;

    // xc = [gnn_out(9), xn(1), feat(31)]
    float xc[41];
    const float* agg = wsf + OFF_AGG + (size_t)g * GOUT;
    #pragma unroll
    for (int m = 0; m < GOUT; m++) xc[m] = sigm(agg[m] + W[W_BN + m]);
    xc[9] = wsf[OFF_XN + g];
    const T* fp = feature + ((size_t)(b * TSTEPS + HIST + t) * NNODE + n) * FEAT;
    #pragma unroll
    for (int i = 0; i < FEAT; i++) xc[10 + i] = cvt(fp[i]);

    float* hbuf = wsf + OFF_H + (size_t)g * HID;
    float h[HID];
    #pragma unroll
    for (int i = 0; i < HID; i++) h[i] = hbuf[i];
    float hmine[16];
    #pragma unroll
    for (int jj = 0; jj < 16; jj++) hmine[jj] = hbuf[(q << 4) + jj];

    __syncthreads();   // all loads of h done before anyone overwrites

    float px = 0.0f;
    for (int jj = 0; jj < 16; jj++) {
        int j = (q << 4) + jj;                       // wave-uniform
        const float* wr = W + W_WIHT + j * 41;
        const float* wz = W + W_WIHT + (64 + j) * 41;
        const float* wg = W + W_WIHT + (128 + j) * 41;
        float ir = W[W_BIH + j], iz = W[W_BIH + 64 + j], ig = W[W_BIH + 128 + j];
        #pragma unroll
        for (int i = 0; i < 41; i++) {
            ir += xc[i] * wr[i]; iz += xc[i] * wz[i]; ig += xc[i] * wg[i];
        }
        const float* vr = W + W_WHHT + j * 64;
        const float* vz = W + W_WHHT + (64 + j) * 64;
        const float* vg = W + W_WHHT + (128 + j) * 64;
        float hr = W[W_BHH + j], hz = W[W_BHH + 64 + j], hg = W[W_BHH + 128 + j];
        #pragma unroll
        for (int i = 0; i < HID; i++) {
            hr += h[i] * vr[i]; hz += h[i] * vz[i]; hg += h[i] * vg[i];
        }
        float r  = sigm(ir + hr);
        float z  = sigm(iz + hz);
        float nn = tanhf(ig + r * hg);
        float hnew = (1.0f - z) * nn + z * hmine[jj];
        hbuf[j] = hnew;
        px += hnew * W[W_WOUT + j];
    }
    lpx[q][lane] = px;
    __syncthreads();
    if (q == 0) {
        float v = lpx[0][lane] + lpx[1][lane] + lpx[2][lane] + lpx[3][lane] + W[W_BOUT];
        wsf[OFF_XN + g] = v;                          // next step's xn
        out[((size_t)b * PRED + t) * NNODE + n] = (OT)v;
    }
}

__global__ __launch_bounds__(256) void k_gru(float* wsf, const void* feature, void* out, int t)
{
    if (wsf[IDX_FLAG] > 0.5f) gru_body(wsf, (const bf16*)feature, (bf16*)out, t);
    else                      gru_body(wsf, (const float*)feature, (float*)out, t);
}

extern "C" void kernel_launch(void* const* d_in, const int* in_sizes, int n_in,
                              void* d_out, int out_size, void* d_ws, size_t ws_size,
                              hipStream_t stream)
{
    float* wsf = (float*)d_ws;
    const void* rain    = d_in[0];
    const void* feature = d_in[1];
    const int*  eidx    = (const int*)d_in[2];
    const void* ea      = d_in[3];
    const void* wm      = d_in[4];
    const void* wsd     = d_in[5];

    hipMemsetAsync(wsf, 0, 16 * sizeof(float), stream);                       // stats + flag area
    hipMemsetAsync(wsf + OFF_H, 0, (size_t)BN * NNODE * HID * sizeof(float), stream);

    k_sniff<<<1, 64, 0, stream>>>(wsf, ea);
    k_weights<<<(W_TOTAL + 255) / 256, 256, 0, stream>>>(wsf,
        d_in[6], d_in[7], d_in[8], d_in[9], d_in[10], d_in[11], d_in[12],
        d_in[13], d_in[14], d_in[15], d_in[16], d_in[17], wm, wsd);
    k_stats<<<NEDGE / 256, 256, 0, stream>>>(wsf, ea);
    k_init<<<(BN * NNODE + 255) / 256, 256, 0, stream>>>(wsf, rain);

    for (int t = 0; t < PRED; t++) {
        hipMemsetAsync(wsf + OFF_AGG, 0, (size_t)BN * NNODE * GOUT * sizeof(float), stream);
        dim3 ge(NEDGE / 256, BN);
        k_edge<<<ge, 256, 0, stream>>>(wsf, eidx, ea, feature, t);
        k_gru<<<(BN * NNODE) / 64, 256, 0, stream>>>(wsf, feature, d_out, t);
    }
}

// Round 3
// 5469.243 us; speedup vs baseline: 1.9379x; 1.9379x over previous
//
#include <hip/hip_runtime.h>
#include <hip/hip_bf16.h>

typedef __hip_bfloat16 bf16;

#define BN    4
#define HIST  24
#define PRED  12
#define NNODE 10000
#define NEDGE 160000
#define FEAT  31      // IN_DIM-1
#define TSTEPS 36     // HIST+PRED
#define EH    32
#define EOUT  30
#define GOUT  9
#define HID   64

// ---- workspace layout (float/int offsets, 4B units) ----
#define IDX_FLAG 4         // 1.0 = inputs are bf16, 0.0 = inputs are f32
#define OFF_W    16
#define W_WE1   0          // 67*32  [i][j]
#define W_BE1   2144       // 32
#define W_WE2T  2176       // 30*32  [k][j] (transposed)
#define W_BE2   3136       // 30
#define W_WN    3166       // 30*9   [k][m]
#define W_BN    3436       // 9
#define W_WIHT  3445       // 192*41 [row][i] (transposed)
#define W_BIH   11317      // 192
#define W_WHHT  11509      // 192*64 [row][i] (transposed)
#define W_BHH   23797      // 192
#define W_WOUT  23989      // 64
#define W_BOUT  24053      // 1
#define W_WM    24054      // 2 wind_mean
#define W_WSD   24056      // 2 wind_std
#define W_TOTAL 24058

#define OFF_XN  24096      // B*N floats (40000)
#define OFF_AGG 64096      // B*N*9 floats (360000) -- fallback path only
#define OFF_H   424096     // B*N*64 floats (2560000), in-place updated
// ---- fast path extras ----
#define OFF_CSR 2984096    // int region
#define RP_IN   (OFF_CSR)            // 10016 (rowptr_in, excl prefix, [N]=E)
#define RP_OUT  (OFF_CSR + 10016)    // 10016
#define CUR_IN  (OFF_CSR + 20032)    // 10016 (fill cursors)
#define CUR_OUT (OFF_CSR + 30048)    // 10016
#define PERM_IN (OFF_CSR + 40064)    // 160000
#define PERM_OUT (OFF_CSR + 200064)  // 160000
#define OFF_F9  3344160              // B*E*12 floats (7,680,000), stride 12 for float4
#define FAST_WS_FLOATS 11024160ull
#define FAST_WS_BYTES  (FAST_WS_FLOATS * 4ull)   // 44.1 MB

__device__ __forceinline__ float cvt(bf16 v)  { return __bfloat162float(v); }
__device__ __forceinline__ float cvt(float v) { return v; }
__device__ __forceinline__ float sigm(float x){ return 1.0f / (1.0f + __expf(-x)); }

// ---- dtype sniff: even bf16 elements of edge_attr are dist in [0.1,1.1] iff bf16 ----
__global__ void k_sniff(float* __restrict__ wsf, const void* __restrict__ ea)
{
    const bf16* p = (const bf16*)ea;
    int lane = threadIdx.x;                   // launched with 64 threads
    float v = __bfloat162float(p[2 * lane]);
    bool ok = (v >= 0.03f) && (v <= 1.3f);
    unsigned long long m = __ballot(ok);
    if (lane == 0) wsf[IDX_FLAG] = (m == ~0ull) ? 1.0f : 0.0f;
}

// ---- convert + transpose all weights -> f32 in ws ----
template<typename T>
__device__ __forceinline__ void weights_body(float* W,
    const T* We1, const T* be1, const T* We2, const T* be2,
    const T* Wn,  const T* bn,  const T* Wih, const T* bih,
    const T* Whh, const T* bhh, const T* Wout, const T* bout,
    const T* wm,  const T* wsd)
{
    int r = blockIdx.x * blockDim.x + threadIdx.x;
    if (r < 2144) { W[W_WE1 + r] = cvt(We1[r]); return; } r -= 2144;
    if (r < 32)   { W[W_BE1 + r] = cvt(be1[r]); return; } r -= 32;
    if (r < 960)  { int k = r / 32, j = r % 32; W[W_WE2T + r] = cvt(We2[j*30 + k]); return; } r -= 960;
    if (r < 30)   { W[W_BE2 + r] = cvt(be2[r]); return; } r -= 30;
    if (r < 270)  { W[W_WN  + r] = cvt(Wn[r]);  return; } r -= 270;
    if (r < 9)    { W[W_BN  + r] = cvt(bn[r]);  return; } r -= 9;
    if (r < 7872) { int row = r / 41, i = r % 41; W[W_WIHT + r] = cvt(Wih[i*192 + row]); return; } r -= 7872;
    if (r < 192)  { W[W_BIH + r] = cvt(bih[r]); return; } r -= 192;
    if (r < 12288){ int row = r / 64, i = r % 64; W[W_WHHT + r] = cvt(Whh[i*192 + row]); return; } r -= 12288;
    if (r < 192)  { W[W_BHH + r] = cvt(bhh[r]); return; } r -= 192;
    if (r < 64)   { W[W_WOUT + r] = cvt(Wout[r]); return; } r -= 64;
    if (r < 1)    { W[W_BOUT] = cvt(bout[0]); return; } r -= 1;
    if (r < 2)    { W[W_WM + r] = cvt(wm[r]); return; } r -= 2;
    if (r < 2)    { W[W_WSD + r] = cvt(wsd[r]); return; }
}

__global__ void k_weights(float* wsf,
    const void* We1, const void* be1, const void* We2, const void* be2,
    const void* Wn,  const void* bn,  const void* Wih, const void* bih,
    const void* Whh, const void* bhh, const void* Wout, const void* bout,
    const void* wm,  const void* wsd)
{
    float* W = wsf + OFF_W;
    if (wsf[IDX_FLAG] > 0.5f)
        weights_body(W, (const bf16*)We1, (const bf16*)be1, (const bf16*)We2, (const bf16*)be2,
                        (const bf16*)Wn,  (const bf16*)bn,  (const bf16*)Wih, (const bf16*)bih,
                        (const bf16*)Whh, (const bf16*)bhh, (const bf16*)Wout, (const bf16*)bout,
                        (const bf16*)wm,  (const bf16*)wsd);
    else
        weights_body(W, (const float*)We1, (const float*)be1, (const float*)We2, (const float*)be2,
                        (const float*)Wn,  (const float*)bn,  (const float*)Wih, (const float*)bih,
                        (const float*)Whh, (const float*)bhh, (const float*)Wout, (const float*)bout,
                        (const float*)wm,  (const float*)wsd);
}

// ---- edge_attr column sums / sumsq ----
template<typename T>
__device__ __forceinline__ void stats_body(float* wsf, const T* ea)
{
    int e = blockIdx.x * 256 + threadIdx.x;
    float d = cvt(ea[2*e]), c = cvt(ea[2*e + 1]);
    float v0 = d, v1 = c, v2 = d*d, v3 = c*c;
    #pragma unroll
    for (int o = 32; o > 0; o >>= 1) {
        v0 += __shfl_down(v0, o);
        v1 += __shfl_down(v1, o);
        v2 += __shfl_down(v2, o);
        v3 += __shfl_down(v3, o);
    }
    if ((threadIdx.x & 63) == 0) {
        unsafeAtomicAdd(&wsf[0], v0);
        unsafeAtomicAdd(&wsf[1], v1);
        unsafeAtomicAdd(&wsf[2], v2);
        unsafeAtomicAdd(&wsf[3], v3);
    }
}

__global__ __launch_bounds__(256) void k_stats(float* wsf, const void* ea)
{
    if (wsf[IDX_FLAG] > 0.5f) stats_body(wsf, (const bf16*)ea);
    else                      stats_body(wsf, (const float*)ea);
}

// ---- init xn state ----
template<typename T>
__device__ __forceinline__ void init_body(float* wsf, const T* rain)
{
    int g = blockIdx.x * blockDim.x + threadIdx.x;
    if (g >= BN * NNODE) return;
    int b = g / NNODE, n = g % NNODE;
    wsf[OFF_XN + g] = cvt(rain[(b * HIST + (HIST - 1)) * NNODE + n]);
}

__global__ void k_init(float* wsf, const void* rain)
{
    if (wsf[IDX_FLAG] > 0.5f) init_body(wsf, (const bf16*)rain);
    else                      init_body(wsf, (const float*)rain);
}

// ---- CSR build (once per launch) ----
__global__ __launch_bounds__(256) void k_csr_hist(int* wsi, const int* __restrict__ eidx)
{
    int e = blockIdx.x * 256 + threadIdx.x;   // E exact
    atomicAdd(&wsi[RP_IN  + eidx[NEDGE + e]], 1);  // in-degree of tgt
    atomicAdd(&wsi[RP_OUT + eidx[e]],         1);  // out-degree of src
}

__global__ __launch_bounds__(256) void k_csr_scan(int* wsi)
{
    int* arr = (blockIdx.x == 0) ? (wsi + RP_IN)  : (wsi + RP_OUT);
    int* cur = (blockIdx.x == 0) ? (wsi + CUR_IN) : (wsi + CUR_OUT);
    __shared__ int tot[256], base[256];
    const int CH = 40;                         // 256*40 = 10240 >= 10000
    int tid = threadIdx.x, st = tid * CH;
    int loc[CH];
    int s = 0;
    #pragma unroll
    for (int i = 0; i < CH; i++) {
        int idx = st + i;
        int v = (idx < NNODE) ? arr[idx] : 0;
        loc[i] = s; s += v;
    }
    tot[tid] = s;
    __syncthreads();
    if (tid == 0) {
        int r = 0;
        for (int i = 0; i < 256; i++) { base[i] = r; r += tot[i]; }
        arr[NNODE] = r;                        // == E
    }
    __syncthreads();
    int b = base[tid];
    #pragma unroll
    for (int i = 0; i < CH; i++) {
        int idx = st + i;
        if (idx < NNODE) { int v = b + loc[i]; arr[idx] = v; cur[idx] = v; }
    }
}

__global__ __launch_bounds__(256) void k_csr_fill(int* wsi, const int* __restrict__ eidx)
{
    int e = blockIdx.x * 256 + threadIdx.x;   // E exact
    int src = eidx[e], tgt = eidx[NEDGE + e];
    int p = atomicAdd(&wsi[CUR_IN  + tgt], 1);
    wsi[PERM_IN + p] = e;
    int q = atomicAdd(&wsi[CUR_OUT + src], 1);
    wsi[PERM_OUT + q] = e;
}

// ---- shared edge-MLP math: returns f9 ----
template<typename T>
__device__ __forceinline__ void edge_mlp(float* wsf, const int* eidx,
                                         const T* ea, const T* feature,
                                         int e, int b, int t, float f9[GOUT])
{
    const float* W = wsf + OFF_W;
    int src = eidx[e], tgt = eidx[NEDGE + e];

    const float invE = 1.0f / (float)NEDGE;
    float s0 = wsf[0], s1 = wsf[1], q0 = wsf[2], q1 = wsf[3];
    float m0 = s0 * invE, m1 = s1 * invE;
    float istd0 = rsqrtf(fmaxf((q0 - s0 * m0) * (1.0f / (NEDGE - 1)), 1e-20f));
    float istd1 = rsqrtf(fmaxf((q1 - s1 * m1) * (1.0f / (NEDGE - 1)), 1e-20f));

    float dist = cvt(ea[2*e]), cdir = cvt(ea[2*e + 1]);
    float ean0 = (dist - m0) * istd0, ean1 = (cdir - m1) * istd1;

    size_t frow = (size_t)(b * TSTEPS + HIST + t) * NNODE;
    const T* fS = feature + (frow + src) * FEAT;
    const T* fT = feature + (frow + tgt) * FEAT;
    float xnS = wsf[OFF_XN + b * NNODE + src];
    float xnT = wsf[OFF_XN + b * NNODE + tgt];

    float speed = cvt(fS[29]) * W[W_WSD + 0] + W[W_WM + 0];
    float direc = cvt(fS[30]) * W[W_WSD + 1] + W[W_WM + 1];
    float theta = fabsf(cdir - direc);
    float ew = fmaxf(3.0f * speed * cosf(theta * 22.5f) / dist, 0.0f);

    const float* We1 = W + W_WE1;
    float acc[EH];
    #pragma unroll
    for (int j = 0; j < EH; j++)
        acc[j] = W[W_BE1 + j] + xnS * We1[j] + xnT * We1[32*EH + j]
               + ean0 * We1[64*EH + j] + ean1 * We1[65*EH + j] + ew * We1[66*EH + j];
    for (int i = 0; i < FEAT; i++) {
        float v = cvt(fS[i]);
        const float* wr = We1 + (1 + i) * EH;
        #pragma unroll
        for (int j = 0; j < EH; j++) acc[j] += v * wr[j];
    }
    for (int i = 0; i < FEAT; i++) {
        float v = cvt(fT[i]);
        const float* wr = We1 + (33 + i) * EH;
        #pragma unroll
        for (int j = 0; j < EH; j++) acc[j] += v * wr[j];
    }
    #pragma unroll
    for (int j = 0; j < EH; j++) acc[j] = sigm(acc[j]);

    #pragma unroll
    for (int m = 0; m < GOUT; m++) f9[m] = 0.0f;
    const float* We2T = W + W_WE2T;
    const float* WnW  = W + W_WN;
    for (int k = 0; k < EOUT; k++) {
        float a = W[W_BE2 + k];
        const float* wr = We2T + k * EH;
        #pragma unroll
        for (int j = 0; j < EH; j++) a += acc[j] * wr[j];
        float ek = sigm(a);
        const float* wn = WnW + k * GOUT;
        #pragma unroll
        for (int m = 0; m < GOUT; m++) f9[m] += ek * wn[m];
    }
}

// ---- FALLBACK edge kernel (atomic scatter) ----
template<typename T>
__device__ __forceinline__ void edge_body(float* wsf, const int* eidx,
                                          const T* ea, const T* feature, int t)
{
    int e = blockIdx.x * 256 + threadIdx.x;
    int b = blockIdx.y;
    float f9[GOUT];
    edge_mlp(wsf, eidx, ea, feature, e, b, t, f9);
    int src = eidx[e], tgt = eidx[NEDGE + e];
    float* aggT = wsf + OFF_AGG + (size_t)(b * NNODE + tgt) * GOUT;
    float* aggS = wsf + OFF_AGG + (size_t)(b * NNODE + src) * GOUT;
    #pragma unroll
    for (int m = 0; m < GOUT; m++) {
        unsafeAtomicAdd(&aggT[m],  f9[m]);
        unsafeAtomicAdd(&aggS[m], -f9[m]);
    }
}

__global__ __launch_bounds__(256) void k_edge(float* wsf, const int* eidx,
                                              const void* ea, const void* feature, int t)
{
    if (wsf[IDX_FLAG] > 0.5f) edge_body(wsf, eidx, (const bf16*)ea, (const bf16*)feature, t);
    else                      edge_body(wsf, eidx, (const float*)ea, (const float*)feature, t);
}

// ---- FAST edge kernel (store f9, no atomics) ----
template<typename T>
__device__ __forceinline__ void edge2_body(float* wsf, const int* eidx,
                                           const T* ea, const T* feature, int t)
{
    int e = blockIdx.x * 256 + threadIdx.x;
    int b = blockIdx.y;
    float f9[GOUT];
    edge_mlp(wsf, eidx, ea, feature, e, b, t, f9);
    float4* p = (float4*)(wsf + OFF_F9 + (size_t)(b * NEDGE + e) * 12);
    p[0] = make_float4(f9[0], f9[1], f9[2], f9[3]);
    p[1] = make_float4(f9[4], f9[5], f9[6], f9[7]);
    p[2] = make_float4(f9[8], 0.0f, 0.0f, 0.0f);
}

__global__ __launch_bounds__(256) void k_edge2(float* wsf, const int* eidx,
                                               const void* ea, const void* feature, int t)
{
    if (wsf[IDX_FLAG] > 0.5f) edge2_body(wsf, eidx, (const bf16*)ea, (const bf16*)feature, t);
    else                      edge2_body(wsf, eidx, (const float*)ea, (const float*)feature, t);
}

// ---- GRU core (shared by both paths); agg[9] already summed, pre-bias/sigmoid ----
template<typename T, typename OT>
__device__ __forceinline__ void gru_core(float* wsf, const T* feature, OT* out, int t,
                                         int lane, int q, int g, int b, int n,
                                         const float agg[GOUT])
{
    __shared__ float lpx[4][64];
    const float* W = wsf + OFF_W;

    float xc[41];
    #pragma unroll
    for (int m = 0; m < GOUT; m++) xc[m] = sigm(agg[m] + W[W_BN + m]);
    xc[9] = wsf[OFF_XN + g];
    const T* fp = feature + ((size_t)(b * TSTEPS + HIST + t) * NNODE + n) * FEAT;
    #pragma unroll
    for (int i = 0; i < FEAT; i++) xc[10 + i] = cvt(fp[i]);

    float* hbuf = wsf + OFF_H + (size_t)g * HID;
    float h[HID];
    #pragma unroll
    for (int i = 0; i < HID; i++) h[i] = hbuf[i];
    float hmine[16];
    #pragma unroll
    for (int jj = 0; jj < 16; jj++) hmine[jj] = hbuf[(q << 4) + jj];

    __syncthreads();   // all loads of h done before anyone overwrites

    float px = 0.0f;
    for (int jj = 0; jj < 16; jj++) {
        int j = (q << 4) + jj;                       // wave-uniform
        const float* wr = W + W_WIHT + j * 41;
        const float* wz = W + W_WIHT + (64 + j) * 41;
        const float* wg = W + W_WIHT + (128 + j) * 41;
        float ir = W[W_BIH + j], iz = W[W_BIH + 64 + j], ig = W[W_BIH + 128 + j];
        #pragma unroll
        for (int i = 0; i < 41; i++) {
            ir += xc[i] * wr[i]; iz += xc[i] * wz[i]; ig += xc[i] * wg[i];
        }
        const float* vr = W + W_WHHT + j * 64;
        const float* vz = W + W_WHHT + (64 + j) * 64;
        const float* vg = W + W_WHHT + (128 + j) * 64;
        float hr = W[W_BHH + j], hz = W[W_BHH + 64 + j], hg = W[W_BHH + 128 + j];
        #pragma unroll
        for (int i = 0; i < HID; i++) {
            hr += h[i] * vr[i]; hz += h[i] * vz[i]; hg += h[i] * vg[i];
        }
        float r  = sigm(ir + hr);
        float z  = sigm(iz + hz);
        float nn = tanhf(ig + r * hg);
        float hnew = (1.0f - z) * nn + z * hmine[jj];
        hbuf[j] = hnew;
        px += hnew * W[W_WOUT + j];
    }
    lpx[q][lane] = px;
    __syncthreads();
    if (q == 0) {
        float v = lpx[0][lane] + lpx[1][lane] + lpx[2][lane] + lpx[3][lane] + W[W_BOUT];
        wsf[OFF_XN + g] = v;
        out[((size_t)b * PRED + t) * NNODE + n] = (OT)v;
    }
}

// ---- FALLBACK GRU: agg from atomic buffer ----
template<typename T, typename OT>
__device__ __forceinline__ void gru_body(float* wsf, const T* feature, OT* out, int t)
{
    int lane = threadIdx.x & 63, q = threadIdx.x >> 6;
    int g = blockIdx.x * 64 + lane;
    int b = g / NNODE, n = g % NNODE;
    float agg[GOUT];
    const float* ap = wsf + OFF_AGG + (size_t)g * GOUT;
    #pragma unroll
    for (int m = 0; m < GOUT; m++) agg[m] = ap[m];
    gru_core(wsf, feature, out, t, lane, q, g, b, n, agg);
}

__global__ __launch_bounds__(256) void k_gru(float* wsf, const void* feature, void* out, int t)
{
    if (wsf[IDX_FLAG] > 0.5f) gru_body(wsf, (const bf16*)feature, (bf16*)out, t);
    else                      gru_body(wsf, (const float*)feature, (float*)out, t);
}

// ---- FAST GRU: gather f9 via CSR ----
template<typename T, typename OT>
__device__ __forceinline__ void gru2_body(float* wsf, const int* wsi, const T* feature, OT* out, int t)
{
    int lane = threadIdx.x & 63, q = threadIdx.x >> 6;
    int g = blockIdx.x * 64 + lane;
    int b = g / NNODE, n = g % NNODE;

    const float* F9b = wsf + OFF_F9 + (size_t)b * NEDGE * 12;
    float agg[GOUT];
    #pragma unroll
    for (int m = 0; m < GOUT; m++) agg[m] = 0.0f;

    int i0 = wsi[RP_IN + n], i1 = wsi[RP_IN + n + 1];
    for (int i = i0; i < i1; i++) {
        int e = wsi[PERM_IN + i];
        const float4* p = (const float4*)(F9b + (size_t)e * 12);
        float4 a = p[0], c = p[1], d = p[2];
        agg[0] += a.x; agg[1] += a.y; agg[2] += a.z; agg[3] += a.w;
        agg[4] += c.x; agg[5] += c.y; agg[6] += c.z; agg[7] += c.w;
        agg[8] += d.x;
    }
    int o0 = wsi[RP_OUT + n], o1 = wsi[RP_OUT + n + 1];
    for (int i = o0; i < o1; i++) {
        int e = wsi[PERM_OUT + i];
        const float4* p = (const float4*)(F9b + (size_t)e * 12);
        float4 a = p[0], c = p[1], d = p[2];
        agg[0] -= a.x; agg[1] -= a.y; agg[2] -= a.z; agg[3] -= a.w;
        agg[4] -= c.x; agg[5] -= c.y; agg[6] -= c.z; agg[7] -= c.w;
        agg[8] -= d.x;
    }
    gru_core(wsf, feature, out, t, lane, q, g, b, n, agg);
}

__global__ __launch_bounds__(256) void k_gru2(float* wsf, const void* feature, void* out, int t)
{
    const int* wsi = (const int*)wsf;
    if (wsf[IDX_FLAG] > 0.5f) gru2_body(wsf, wsi, (const bf16*)feature, (bf16*)out, t);
    else                      gru2_body(wsf, wsi, (const float*)feature, (float*)out, t);
}

extern "C" void kernel_launch(void* const* d_in, const int* in_sizes, int n_in,
                              void* d_out, int out_size, void* d_ws, size_t ws_size,
                              hipStream_t stream)
{
    float* wsf = (float*)d_ws;
    int*   wsi = (int*)d_ws;
    const void* rain    = d_in[0];
    const void* feature = d_in[1];
    const int*  eidx    = (const int*)d_in[2];
    const void* ea      = d_in[3];
    const void* wm      = d_in[4];
    const void* wsd     = d_in[5];

    bool fast = (ws_size >= FAST_WS_BYTES);

    hipMemsetAsync(wsf, 0, 16 * sizeof(float), stream);
    hipMemsetAsync(wsf + OFF_H, 0, (size_t)BN * NNODE * HID * sizeof(float), stream);

    k_sniff<<<1, 64, 0, stream>>>(wsf, ea);
    k_weights<<<(W_TOTAL + 255) / 256, 256, 0, stream>>>(wsf,
        d_in[6], d_in[7], d_in[8], d_in[9], d_in[10], d_in[11], d_in[12],
        d_in[13], d_in[14], d_in[15], d_in[16], d_in[17], wm, wsd);
    k_stats<<<NEDGE / 256, 256, 0, stream>>>(wsf, ea);
    k_init<<<(BN * NNODE + 255) / 256, 256, 0, stream>>>(wsf, rain);

    if (fast) {
        // CSR build (once per launch; ws re-poisoned each call)
        hipMemsetAsync(wsi + RP_IN, 0, 20032 * sizeof(int), stream);   // rp_in + rp_out
        k_csr_hist<<<NEDGE / 256, 256, 0, stream>>>(wsi, eidx);
        k_csr_scan<<<2, 256, 0, stream>>>(wsi);
        k_csr_fill<<<NEDGE / 256, 256, 0, stream>>>(wsi, eidx);

        for (int t = 0; t < PRED; t++) {
            dim3 ge(NEDGE / 256, BN);
            k_edge2<<<ge, 256, 0, stream>>>(wsf, eidx, ea, feature, t);
            k_gru2<<<(BN * NNODE) / 64, 256, 0, stream>>>(wsf, feature, d_out, t);
        }
    } else {
        for (int t = 0; t < PRED; t++) {
            hipMemsetAsync(wsf + OFF_AGG, 0, (size_t)BN * NNODE * GOUT * sizeof(float), stream);
            dim3 ge(NEDGE / 256, BN);
            k_edge<<<ge, 256, 0, stream>>>(wsf, eidx, ea, feature, t);
            k_gru<<<(BN * NNODE) / 64, 256, 0, stream>>>(wsf, feature, d_out, t);
        }
    }
}

// Round 4
// 3738.281 us; speedup vs baseline: 2.8352x; 1.4630x over previous
//
#include <hip/hip_runtime.h>
#include <hip/hip_bf16.h>

typedef __hip_bfloat16 bf16;

#define BN    4
#define HIST  24
#define PRED  12
#define NNODE 10000
#define NEDGE 160000
#define FEAT  31
#define TSTEPS 36
#define EH    32
#define EOUT  30
#define GOUT  9
#define HID   64

#define IDX_FLAG 4
#define OFF_W    16
#define W_WE1   0
#define W_BE1   2144
#define W_WE2T  2176
#define W_BE2   3136
#define W_WN    3166
#define W_BN    3436
#define W_WIHT  3445
#define W_BIH   11317
#define W_WHHT  11509
#define W_BHH   23797
#define W_WOUT  23989
#define W_BOUT  24053
#define W_WM    24054
#define W_WSD   24056
#define W_TOTAL 24058

#define OFF_XN  24096
#define OFF_AGG 64096
#define OFF_H   424096
#define OFF_CSR 2984096
#define RP_IN   (OFF_CSR)
#define RP_OUT  (OFF_CSR + 10016)
#define CUR_IN  (OFF_CSR + 20032)
#define CUR_OUT (OFF_CSR + 30048)
#define PERM_IN (OFF_CSR + 40064)
#define PERM_OUT (OFF_CSR + 200064)
#define OFF_F9  3344160
#define FAST_WS_FLOATS 11024160ull
#define FAST_WS_BYTES  (FAST_WS_FLOATS * 4ull)
#define IPOS_IN  3344160
#define IPOS_OUT 3504160
#define OFF_PST  3664160
#define OFF_WIND 6224160
#define OFF_F9I  6304160
#define OFF_F9O  11424160
#define NEW_WS_FLOATS 16544160ull
#define NEW_WS_BYTES (NEW_WS_FLOATS * 4ull)

__device__ __forceinline__ float cvt(bf16 v)  { return __bfloat162float(v); }
__device__ __forceinline__ float cvt(float v) { return v; }
__device__ __forceinline__ float sigm(float x){ return 1.0f / (1.0f + __expf(-x)); }
__device__ __forceinline__ unsigned f2b1(float x){
    unsigned u = __float_as_uint(x);
    return (u + 0x7fffu + ((u >> 16) & 1u)) >> 16;
}
__device__ __forceinline__ float blo(unsigned u){ return __uint_as_float(u << 16); }
__device__ __forceinline__ float bhi(unsigned u){ return __uint_as_float(u & 0xffff0000u); }

__global__ void k_sniff(float* __restrict__ wsf, const void* __restrict__ ea)
{
    const bf16* p = (const bf16*)ea;
    int lane = threadIdx.x;
    float v = __bfloat162float(p[2 * lane]);
    bool ok = (v >= 0.03f) && (v <= 1.3f);
    unsigned long long m = __ballot(ok);
    if (lane == 0) wsf[IDX_FLAG] = (m == ~0ull) ? 1.0f : 0.0f;
}

template<typename T>
__device__ __forceinline__ void weights_body(float* W,
    const T* We1, const T* be1, const T* We2, const T* be2,
    const T* Wn,  const T* bn,  const T* Wih, const T* bih,
    const T* Whh, const T* bhh, const T* Wout, const T* bout,
    const T* wm,  const T* wsd)
{
    int r = blockIdx.x * blockDim.x + threadIdx.x;
    if (r < 2144) { W[W_WE1 + r] = cvt(We1[r]); return; } r -= 2144;
    if (r < 32)   { W[W_BE1 + r] = cvt(be1[r]); return; } r -= 32;
    if (r < 960)  { int k = r / 32, j = r % 32; W[W_WE2T + r] = cvt(We2[j*30 + k]); return; } r -= 960;
    if (r < 30)   { W[W_BE2 + r] = cvt(be2[r]); return; } r -= 30;
    if (r < 270)  { W[W_WN  + r] = cvt(Wn[r]);  return; } r -= 270;
    if (r < 9)    { W[W_BN  + r] = cvt(bn[r]);  return; } r -= 9;
    if (r < 7872) { int row = r / 41, i = r % 41; W[W_WIHT + r] = cvt(Wih[i*192 + row]); return; } r -= 7872;
    if (r < 192)  { W[W_BIH + r] = cvt(bih[r]); return; } r -= 192;
    if (r < 12288){ int row = r / 64, i = r % 64; W[W_WHHT + r] = cvt(Whh[i*192 + row]); return; } r -= 12288;
    if (r < 192)  { W[W_BHH + r] = cvt(bhh[r]); return; } r -= 192;
    if (r < 64)   { W[W_WOUT + r] = cvt(Wout[r]); return; } r -= 64;
    if (r < 1)    { W[W_BOUT] = cvt(bout[0]); return; } r -= 1;
    if (r < 2)    { W[W_WM + r] = cvt(wm[r]); return; } r -= 2;
    if (r < 2)    { W[W_WSD + r] = cvt(wsd[r]); return; }
}

__global__ void k_weights(float* wsf,
    const void* We1, const void* be1, const void* We2, const void* be2,
    const void* Wn,  const void* bn,  const void* Wih, const void* bih,
    const void* Whh, const void* bhh, const void* Wout, const void* bout,
    const void* wm,  const void* wsd)
{
    float* W = wsf + OFF_W;
    if (wsf[IDX_FLAG] > 0.5f)
        weights_body(W, (const bf16*)We1, (const bf16*)be1, (const bf16*)We2, (const bf16*)be2,
                        (const bf16*)Wn,  (const bf16*)bn,  (const bf16*)Wih, (const bf16*)bih,
                        (const bf16*)Whh, (const bf16*)bhh, (const bf16*)Wout, (const bf16*)bout,
                        (const bf16*)wm,  (const bf16*)wsd);
    else
        weights_body(W, (const float*)We1, (const float*)be1, (const float*)We2, (const float*)be2,
                        (const float*)Wn,  (const float*)bn,  (const float*)Wih, (const float*)bih,
                        (const float*)Whh, (const float*)bhh, (const float*)Wout, (const float*)bout,
                        (const float*)wm,  (const float*)wsd);
}

template<typename T>
__device__ __forceinline__ void stats_body(float* wsf, const T* ea)
{
    int e = blockIdx.x * 256 + threadIdx.x;
    float d = cvt(ea[2*e]), c = cvt(ea[2*e + 1]);
    float v0 = d, v1 = c, v2 = d*d, v3 = c*c;
    #pragma unroll
    for (int o = 32; o > 0; o >>= 1) {
        v0 += __shfl_down(v0, o);
        v1 += __shfl_down(v1, o);
        v2 += __shfl_down(v2, o);
        v3 += __shfl_down(v3, o);
    }
    if ((threadIdx.x & 63) == 0) {
        unsafeAtomicAdd(&wsf[0], v0);
        unsafeAtomicAdd(&wsf[1], v1);
        unsafeAtomicAdd(&wsf[2], v2);
        unsafeAtomicAdd(&wsf[3], v3);
    }
}

__global__ __launch_bounds__(256) void k_stats(float* wsf, const void* ea)
{
    if (wsf[IDX_FLAG] > 0.5f) stats_body(wsf, (const bf16*)ea);
    else                      stats_body(wsf, (const float*)ea);
}

template<typename T>
__device__ __forceinline__ void init_body(float* wsf, const T* rain)
{
    int g = blockIdx.x * blockDim.x + threadIdx.x;
    if (g >= BN * NNODE) return;
    int b = g / NNODE, n = g % NNODE;
    wsf[OFF_XN + g] = cvt(rain[(b * HIST + (HIST - 1)) * NNODE + n]);
}

__global__ void k_init(float* wsf, const void* rain)
{
    if (wsf[IDX_FLAG] > 0.5f) init_body(wsf, (const bf16*)rain);
    else                      init_body(wsf, (const float*)rain);
}

__global__ __launch_bounds__(256) void k_csr_hist(int* wsi, const int* __restrict__ eidx)
{
    int e = blockIdx.x * 256 + threadIdx.x;
    atomicAdd(&wsi[RP_IN  + eidx[NEDGE + e]], 1);
    atomicAdd(&wsi[RP_OUT + eidx[e]],         1);
}

__global__ __launch_bounds__(256) void k_csr_scan(int* wsi)
{
    int* arr = (blockIdx.x == 0) ? (wsi + RP_IN)  : (wsi + RP_OUT);
    int* cur = (blockIdx.x == 0) ? (wsi + CUR_IN) : (wsi + CUR_OUT);
    __shared__ int tot[256], base[256];
    const int CH = 40;
    int tid = threadIdx.x, st = tid * CH;
    int loc[CH];
    int s = 0;
    #pragma unroll
    for (int i = 0; i < CH; i++) {
        int idx = st + i;
        int v = (idx < NNODE) ? arr[idx] : 0;
        loc[i] = s; s += v;
    }
    tot[tid] = s;
    __syncthreads();
    if (tid == 0) {
        int r = 0;
        for (int i = 0; i < 256; i++) { base[i] = r; r += tot[i]; }
        arr[NNODE] = r;
    }
    __syncthreads();
    int b = base[tid];
    #pragma unroll
    for (int i = 0; i < CH; i++) {
        int idx = st + i;
        if (idx < NNODE) { int v = b + loc[i]; arr[idx] = v; cur[idx] = v; }
    }
}

__global__ __launch_bounds__(256) void k_csr_fill(int* wsi, const int* __restrict__ eidx)
{
    int e = blockIdx.x * 256 + threadIdx.x;
    int src = eidx[e], tgt = eidx[NEDGE + e];
    int p = atomicAdd(&wsi[CUR_IN  + tgt], 1);
    wsi[PERM_IN + p] = e;
    wsi[IPOS_IN + e] = p;
    int q = atomicAdd(&wsi[CUR_OUT + src], 1);
    wsi[PERM_OUT + q] = e;
    wsi[IPOS_OUT + e] = q;
}

template<typename T>
__device__ __forceinline__ void edge_mlp(float* wsf, const int* eidx,
                                         const T* ea, const T* feature,
                                         int e, int b, int t, float f9[GOUT])
{
    const float* W = wsf + OFF_W;
    int src = eidx[e], tgt = eidx[NEDGE + e];

    const float invE = 1.0f / (float)NEDGE;
    float s0 = wsf[0], s1 = wsf[1], q0 = wsf[2], q1 = wsf[3];
    float m0 = s0 * invE, m1 = s1 * invE;
    float istd0 = rsqrtf(fmaxf((q0 - s0 * m0) * (1.0f / (NEDGE - 1)), 1e-20f));
    float istd1 = rsqrtf(fmaxf((q1 - s1 * m1) * (1.0f / (NEDGE - 1)), 1e-20f));

    float dist = cvt(ea[2*e]), cdir = cvt(ea[2*e + 1]);
    float ean0 = (dist - m0) * istd0, ean1 = (cdir - m1) * istd1;

    size_t frow = (size_t)(b * TSTEPS + HIST + t) * NNODE;
    const T* fS = feature + (frow + src) * FEAT;
    const T* fT = feature + (frow + tgt) * FEAT;
    float xnS = wsf[OFF_XN + b * NNODE + src];
    float xnT = wsf[OFF_XN + b * NNODE + tgt];

    float speed = cvt(fS[29]) * W[W_WSD + 0] + W[W_WM + 0];
    float direc = cvt(fS[30]) * W[W_WSD + 1] + W[W_WM + 1];
    float theta = fabsf(cdir - direc);
    float ew = fmaxf(3.0f * speed * cosf(theta * 22.5f) / dist, 0.0f);

    const float* We1 = W + W_WE1;
    float acc[EH];
    #pragma unroll
    for (int j = 0; j < EH; j++)
        acc[j] = W[W_BE1 + j] + xnS * We1[j] + xnT * We1[32*EH + j]
               + ean0 * We1[64*EH + j] + ean1 * We1[65*EH + j] + ew * We1[66*EH + j];
    for (int i = 0; i < FEAT; i++) {
        float v = cvt(fS[i]);
        const float* wr = We1 + (1 + i) * EH;
        #pragma unroll
        for (int j = 0; j < EH; j++) acc[j] += v * wr[j];
    }
    for (int i = 0; i < FEAT; i++) {
        float v = cvt(fT[i]);
        const float* wr = We1 + (33 + i) * EH;
        #pragma unroll
        for (int j = 0; j < EH; j++) acc[j] += v * wr[j];
    }
    #pragma unroll
    for (int j = 0; j < EH; j++) acc[j] = sigm(acc[j]);

    #pragma unroll
    for (int m = 0; m < GOUT; m++) f9[m] = 0.0f;
    const float* We2T = W + W_WE2T;
    const float* WnW  = W + W_WN;
    for (int k = 0; k < EOUT; k++) {
        float a = W[W_BE2 + k];
        const float* wr = We2T + k * EH;
        #pragma unroll
        for (int j = 0; j < EH; j++) a += acc[j] * wr[j];
        float ek = sigm(a);
        const float* wn = WnW + k * GOUT;
        #pragma unroll
        for (int m = 0; m < GOUT; m++) f9[m] += ek * wn[m];
    }
}

template<typename T>
__device__ __forceinline__ void edge_body(float* wsf, const int* eidx,
                                          const T* ea, const T* feature, int t)
{
    int e = blockIdx.x * 256 + threadIdx.x;
    int b = blockIdx.y;
    float f9[GOUT];
    edge_mlp(wsf, eidx, ea, feature, e, b, t, f9);
    int src = eidx[e], tgt = eidx[NEDGE + e];
    float* aggT = wsf + OFF_AGG + (size_t)(b * NNODE + tgt) * GOUT;
    float* aggS = wsf + OFF_AGG + (size_t)(b * NNODE + src) * GOUT;
    #pragma unroll
    for (int m = 0; m < GOUT; m++) {
        unsafeAtomicAdd(&aggT[m],  f9[m]);
        unsafeAtomicAdd(&aggS[m], -f9[m]);
    }
}

__global__ __launch_bounds__(256) void k_edge(float* wsf, const int* eidx,
                                              const void* ea, const void* feature, int t)
{
    if (wsf[IDX_FLAG] > 0.5f) edge_body(wsf, eidx, (const bf16*)ea, (const bf16*)feature, t);
    else                      edge_body(wsf, eidx, (const float*)ea, (const float*)feature, t);
}

template<typename T>
__device__ __forceinline__ void edge2_body(float* wsf, const int* eidx,
                                           const T* ea, const T* feature, int t)
{
    int e = blockIdx.x * 256 + threadIdx.x;
    int b = blockIdx.y;
    float f9[GOUT];
    edge_mlp(wsf, eidx, ea, feature, e, b, t, f9);
    float4* p = (float4*)(wsf + OFF_F9 + (size_t)(b * NEDGE + e) * 12);
    p[0] = make_float4(f9[0], f9[1], f9[2], f9[3]);
    p[1] = make_float4(f9[4], f9[5], f9[6], f9[7]);
    p[2] = make_float4(f9[8], 0.0f, 0.0f, 0.0f);
}

__global__ __launch_bounds__(256) void k_edge2(float* wsf, const int* eidx,
                                               const void* ea, const void* feature, int t)
{
    if (wsf[IDX_FLAG] > 0.5f) edge2_body(wsf, eidx, (const bf16*)ea, (const bf16*)feature, t);
    else                      edge2_body(wsf, eidx, (const float*)ea, (const float*)feature, t);
}

// ---- NEW: per-node precompute pS/pT + wind ----
template<typename T>
__device__ __forceinline__ void node_body(float* wsf, const T* feature, int t, uint4* sfeat)
{
    int tid = threadIdx.x;
    int base = blockIdx.x * 256;
    int b = blockIdx.y;
    int n = base + tid;
    size_t frow = (size_t)(b * TSTEPS + HIST + t) * NNODE;
    const int rowB = FEAT * (int)sizeof(T);
    int nvalid = min(256, NNODE - base);
    int vbytes = nvalid * rowB;                   // 256*rowB or 16*rowB: both %16==0

    const uint4* gsrc = (const uint4*)((const char*)feature + (frow + base) * rowB);
    for (int c = tid; c * 16 < vbytes; c += 256) sfeat[c] = gsrc[c];
    __syncthreads();
    if (n >= NNODE) return;

    const T* srow = (const T*)((const char*)sfeat + (size_t)tid * rowB);
    float x[32];
    x[0] = wsf[OFF_XN + b * NNODE + n];
    #pragma unroll
    for (int i = 0; i < FEAT; i++) x[1 + i] = cvt(srow[i]);

    const float* W = wsf + OFF_W;
    float acc[64];
    #pragma unroll
    for (int j = 0; j < 32; j++) acc[j] = W[W_BE1 + j];
    #pragma unroll
    for (int j = 0; j < 32; j++) acc[32 + j] = 0.0f;
    #pragma unroll
    for (int i = 0; i < 32; i++) {
        float v = x[i];
        const float* wS = W + W_WE1 + i * EH;          // compile-time offsets -> s_load
        const float* wT = W + W_WE1 + (32 + i) * EH;
        #pragma unroll
        for (int j = 0; j < 32; j++) { acc[j] += v * wS[j]; acc[32 + j] += v * wT[j]; }
    }

    float4* prow = (float4*)(wsf + OFF_PST + (size_t)(b * NNODE + n) * 64);
    #pragma unroll
    for (int jv = 0; jv < 16; jv++)
        prow[jv] = make_float4(acc[jv*4], acc[jv*4+1], acc[jv*4+2], acc[jv*4+3]);

    float speed = x[30] * W[W_WSD + 0] + W[W_WM + 0];
    float direc = x[31] * W[W_WSD + 1] + W[W_WM + 1];
    ((float2*)(wsf + OFF_WIND))[b * NNODE + n] = make_float2(speed, direc);
}

__global__ __launch_bounds__(256) void k_node(float* wsf, const void* feature, int t)
{
    __shared__ uint4 sfeat[1984];
    if (wsf[IDX_FLAG] > 0.5f) node_body(wsf, (const bf16*)feature, t, sfeat);
    else                      node_body(wsf, (const float*)feature, t, sfeat);
}

// ---- NEW edge kernel: from pS/pT, bf16 f9 stores into CSR-ordered slots ----
template<typename T>
__device__ __forceinline__ void edge3_body(float* wsf, const int* wsi, const int* eidx,
                                           const T* ea, int t)
{
    int e = blockIdx.x * 256 + threadIdx.x;
    int b = blockIdx.y;
    const float* W = wsf + OFF_W;

    int src = eidx[e], tgt = eidx[NEDGE + e];
    int ipi = wsi[IPOS_IN + e], ipo = wsi[IPOS_OUT + e];

    const float invE = 1.0f / (float)NEDGE;
    float s0 = wsf[0], s1 = wsf[1], q0 = wsf[2], q1 = wsf[3];
    float m0 = s0 * invE, m1 = s1 * invE;
    float istd0 = rsqrtf(fmaxf((q0 - s0 * m0) * (1.0f / (NEDGE - 1)), 1e-20f));
    float istd1 = rsqrtf(fmaxf((q1 - s1 * m1) * (1.0f / (NEDGE - 1)), 1e-20f));

    float dist = cvt(ea[2*e]), cdir = cvt(ea[2*e + 1]);
    float ean0 = (dist - m0) * istd0, ean1 = (cdir - m1) * istd1;

    float2 wv = ((const float2*)(wsf + OFF_WIND))[b * NNODE + src];
    float theta = fabsf(cdir - wv.y);
    float ew = fmaxf(3.0f * wv.x * cosf(theta * 22.5f) / dist, 0.0f);

    const float4* ps4 = (const float4*)(wsf + OFF_PST + (size_t)(b * NNODE + src) * 64);
    const float4* pt4 = (const float4*)(wsf + OFF_PST + (size_t)(b * NNODE + tgt) * 64) + 8;

    float l1[EH];
    #pragma unroll
    for (int jv = 0; jv < 8; jv++) {
        float4 a = ps4[jv], c = pt4[jv];
        l1[jv*4+0] = a.x + c.x; l1[jv*4+1] = a.y + c.y;
        l1[jv*4+2] = a.z + c.z; l1[jv*4+3] = a.w + c.w;
    }
    const float* w64 = W + W_WE1 + 64*EH;
    const float* w65 = W + W_WE1 + 65*EH;
    const float* w66 = W + W_WE1 + 66*EH;
    #pragma unroll
    for (int j = 0; j < EH; j++)
        l1[j] = sigm(l1[j] + ean0 * w64[j] + ean1 * w65[j] + ew * w66[j]);

    float f9[GOUT];
    #pragma unroll
    for (int m = 0; m < GOUT; m++) f9[m] = 0.0f;
    const float* We2T = W + W_WE2T;
    const float* WnW  = W + W_WN;
    for (int k = 0; k < EOUT; k++) {
        float a = W[W_BE2 + k];
        const float* wr = We2T + k * EH;
        #pragma unroll
        for (int j = 0; j < EH; j++) a += l1[j] * wr[j];
        float ek = sigm(a);
        const float* wn = WnW + k * GOUT;
        #pragma unroll
        for (int m = 0; m < GOUT; m++) f9[m] += ek * wn[m];
    }

    unsigned u0 = f2b1(f9[0]) | (f2b1(f9[1]) << 16);
    unsigned u1 = f2b1(f9[2]) | (f2b1(f9[3]) << 16);
    unsigned u2 = f2b1(f9[4]) | (f2b1(f9[5]) << 16);
    unsigned u3 = f2b1(f9[6]) | (f2b1(f9[7]) << 16);
    unsigned u4 = f2b1(f9[8]);

    unsigned* pi = (unsigned*)(wsf + OFF_F9I) + ((size_t)b * NEDGE + ipi) * 8;
    ((uint4*)pi)[0] = make_uint4(u0, u1, u2, u3);
    pi[4] = u4;
    unsigned* po = (unsigned*)(wsf + OFF_F9O) + ((size_t)b * NEDGE + ipo) * 8;
    ((uint4*)po)[0] = make_uint4(u0, u1, u2, u3);
    po[4] = u4;
}

__global__ __launch_bounds__(256) void k_edge3(float* wsf, const int* eidx,
                                               const void* ea, int t)
{
    const int* wsi = (const int*)wsf;
    if (wsf[IDX_FLAG] > 0.5f) edge3_body(wsf, wsi, eidx, (const bf16*)ea, t);
    else                      edge3_body(wsf, wsi, eidx, (const float*)ea, t);
}

// ---- GRU core (R2/R3 fallback) ----
template<typename T, typename OT>
__device__ __forceinline__ void gru_core(float* wsf, const T* feature, OT* out, int t,
                                         int lane, int q, int g, int b, int n,
                                         const float agg[GOUT])
{
    __shared__ float lpx[4][64];
    const float* W = wsf + OFF_W;

    float xc[41];
    #pragma unroll
    for (int m = 0; m < GOUT; m++) xc[m] = sigm(agg[m] + W[W_BN + m]);
    xc[9] = wsf[OFF_XN + g];
    const T* fp = feature + ((size_t)(b * TSTEPS + HIST + t) * NNODE + n) * FEAT;
    #pragma unroll
    for (int i = 0; i < FEAT; i++) xc[10 + i] = cvt(fp[i]);

    float* hbuf = wsf + OFF_H + (size_t)g * HID;
    float h[HID];
    #pragma unroll
    for (int i = 0; i < HID; i++) h[i] = hbuf[i];
    float hmine[16];
    #pragma unroll
    for (int jj = 0; jj < 16; jj++) hmine[jj] = hbuf[(q << 4) + jj];

    __syncthreads();

    float px = 0.0f;
    for (int jj = 0; jj < 16; jj++) {
        int j = (q << 4) + jj;
        const float* wr = W + W_WIHT + j * 41;
        const float* wz = W + W_WIHT + (64 + j) * 41;
        const float* wg = W + W_WIHT + (128 + j) * 41;
        float ir = W[W_BIH + j], iz = W[W_BIH + 64 + j], ig = W[W_BIH + 128 + j];
        #pragma unroll
        for (int i = 0; i < 41; i++) {
            ir += xc[i] * wr[i]; iz += xc[i] * wz[i]; ig += xc[i] * wg[i];
        }
        const float* vr = W + W_WHHT + j * 64;
        const float* vz = W + W_WHHT + (64 + j) * 64;
        const float* vg = W + W_WHHT + (128 + j) * 64;
        float hr = W[W_BHH + j], hz = W[W_BHH + 64 + j], hg = W[W_BHH + 128 + j];
        #pragma unroll
        for (int i = 0; i < HID; i++) {
            hr += h[i] * vr[i]; hz += h[i] * vz[i]; hg += h[i] * vg[i];
        }
        float r  = sigm(ir + hr);
        float z  = sigm(iz + hz);
        float nn = tanhf(ig + r * hg);
        float hnew = (1.0f - z) * nn + z * hmine[jj];
        hbuf[j] = hnew;
        px += hnew * W[W_WOUT + j];
    }
    lpx[q][lane] = px;
    __syncthreads();
    if (q == 0) {
        float v = lpx[0][lane] + lpx[1][lane] + lpx[2][lane] + lpx[3][lane] + W[W_BOUT];
        wsf[OFF_XN + g] = v;
        out[((size_t)b * PRED + t) * NNODE + n] = (OT)v;
    }
}

// ---- GRU core (new): uniform weight indices via readfirstlane -> s_load ----
template<typename T, typename OT>
__device__ __forceinline__ void gru_core3(float* wsf, const T* feature, OT* out, int t,
                                          int lane, int q, int g, int b, int n,
                                          const float agg[GOUT])
{
    __shared__ float lpx[4][64];
    const float* W = wsf + OFF_W;
    int jq = __builtin_amdgcn_readfirstlane(q);

    float xc[41];
    #pragma unroll
    for (int m = 0; m < GOUT; m++) xc[m] = sigm(agg[m] + W[W_BN + m]);
    xc[9] = wsf[OFF_XN + g];
    const T* fp = feature + ((size_t)(b * TSTEPS + HIST + t) * NNODE + n) * FEAT;
    #pragma unroll
    for (int i = 0; i < FEAT; i++) xc[10 + i] = cvt(fp[i]);

    float* hbuf = wsf + OFF_H + (size_t)g * HID;
    float h[HID];
    #pragma unroll
    for (int i = 0; i < HID; i++) h[i] = hbuf[i];
    float hmine[16];
    #pragma unroll
    for (int jj = 0; jj < 16; jj++) hmine[jj] = hbuf[(q << 4) + jj];

    __syncthreads();

    float px = 0.0f;
    for (int jj = 0; jj < 16; jj++) {
        int j = (jq << 4) + jj;                       // SGPR math -> s_load weights
        const float* wr = W + W_WIHT + j * 41;
        const float* wz = W + W_WIHT + (64 + j) * 41;
        const float* wg = W + W_WIHT + (128 + j) * 41;
        float ir = W[W_BIH + j], iz = W[W_BIH + 64 + j], ig = W[W_BIH + 128 + j];
        #pragma unroll
        for (int i = 0; i < 41; i++) {
            ir += xc[i] * wr[i]; iz += xc[i] * wz[i]; ig += xc[i] * wg[i];
        }
        const float* vr = W + W_WHHT + j * 64;
        const float* vz = W + W_WHHT + (64 + j) * 64;
        const float* vg = W + W_WHHT + (128 + j) * 64;
        float hr = W[W_BHH + j], hz = W[W_BHH + 64 + j], hg = W[W_BHH + 128 + j];
        #pragma unroll
        for (int i = 0; i < HID; i++) {
            hr += h[i] * vr[i]; hz += h[i] * vz[i]; hg += h[i] * vg[i];
        }
        float r  = sigm(ir + hr);
        float z  = sigm(iz + hz);
        float nn = tanhf(ig + r * hg);
        float hnew = (1.0f - z) * nn + z * hmine[jj];
        hbuf[j] = hnew;
        px += hnew * W[W_WOUT + j];
    }
    lpx[q][lane] = px;
    __syncthreads();
    if (q == 0) {
        float v = lpx[0][lane] + lpx[1][lane] + lpx[2][lane] + lpx[3][lane] + W[W_BOUT];
        wsf[OFF_XN + g] = v;
        out[((size_t)b * PRED + t) * NNODE + n] = (OT)v;
    }
}

template<typename T, typename OT>
__device__ __forceinline__ void gru_body(float* wsf, const T* feature, OT* out, int t)
{
    int lane = threadIdx.x & 63, q = threadIdx.x >> 6;
    int g = blockIdx.x * 64 + lane;
    int b = g / NNODE, n = g % NNODE;
    float agg[GOUT];
    const float* ap = wsf + OFF_AGG + (size_t)g * GOUT;
    #pragma unroll
    for (int m = 0; m < GOUT; m++) agg[m] = ap[m];
    gru_core(wsf, feature, out, t, lane, q, g, b, n, agg);
}

__global__ __launch_bounds__(256) void k_gru(float* wsf, const void* feature, void* out, int t)
{
    if (wsf[IDX_FLAG] > 0.5f) gru_body(wsf, (const bf16*)feature, (bf16*)out, t);
    else                      gru_body(wsf, (const float*)feature, (float*)out, t);
}

template<typename T, typename OT>
__device__ __forceinline__ void gru2_body(float* wsf, const int* wsi, const T* feature, OT* out, int t)
{
    int lane = threadIdx.x & 63, q = threadIdx.x >> 6;
    int g = blockIdx.x * 64 + lane;
    int b = g / NNODE, n = g % NNODE;

    const float* F9b = wsf + OFF_F9 + (size_t)b * NEDGE * 12;
    float agg[GOUT];
    #pragma unroll
    for (int m = 0; m < GOUT; m++) agg[m] = 0.0f;

    int i0 = wsi[RP_IN + n], i1 = wsi[RP_IN + n + 1];
    for (int i = i0; i < i1; i++) {
        int e = wsi[PERM_IN + i];
        const float4* p = (const float4*)(F9b + (size_t)e * 12);
        float4 a = p[0], c = p[1], d = p[2];
        agg[0] += a.x; agg[1] += a.y; agg[2] += a.z; agg[3] += a.w;
        agg[4] += c.x; agg[5] += c.y; agg[6] += c.z; agg[7] += c.w;
        agg[8] += d.x;
    }
    int o0 = wsi[RP_OUT + n], o1 = wsi[RP_OUT + n + 1];
    for (int i = o0; i < o1; i++) {
        int e = wsi[PERM_OUT + i];
        const float4* p = (const float4*)(F9b + (size_t)e * 12);
        float4 a = p[0], c = p[1], d = p[2];
        agg[0] -= a.x; agg[1] -= a.y; agg[2] -= a.z; agg[3] -= a.w;
        agg[4] -= c.x; agg[5] -= c.y; agg[6] -= c.z; agg[7] -= c.w;
        agg[8] -= d.x;
    }
    gru_core(wsf, feature, out, t, lane, q, g, b, n, agg);
}

__global__ __launch_bounds__(256) void k_gru2(float* wsf, const void* feature, void* out, int t)
{
    const int* wsi = (const int*)wsf;
    if (wsf[IDX_FLAG] > 0.5f) gru2_body(wsf, wsi, (const bf16*)feature, (bf16*)out, t);
    else                      gru2_body(wsf, wsi, (const float*)feature, (float*)out, t);
}

template<typename T, typename OT>
__device__ __forceinline__ void gru3_body(float* wsf, const int* wsi, const T* feature, OT* out, int t)
{
    int lane = threadIdx.x & 63, q = threadIdx.x >> 6;
    int g = blockIdx.x * 64 + lane;
    int b = g / NNODE, n = g % NNODE;

    const unsigned* f9i = (const unsigned*)(wsf + OFF_F9I) + (size_t)b * NEDGE * 8;
    const unsigned* f9o = (const unsigned*)(wsf + OFF_F9O) + (size_t)b * NEDGE * 8;
    float agg[GOUT];
    #pragma unroll
    for (int m = 0; m < GOUT; m++) agg[m] = 0.0f;

    int i0 = wsi[RP_IN + n], i1 = wsi[RP_IN + n + 1];
    for (int p = i0; p < i1; p++) {
        const unsigned* s = f9i + (size_t)p * 8;
        uint4 a = *(const uint4*)s;
        unsigned e8 = s[4];
        agg[0] += blo(a.x); agg[1] += bhi(a.x);
        agg[2] += blo(a.y); agg[3] += bhi(a.y);
        agg[4] += blo(a.z); agg[5] += bhi(a.z);
        agg[6] += blo(a.w); agg[7] += bhi(a.w);
        agg[8] += blo(e8);
    }
    int o0 = wsi[RP_OUT + n], o1 = wsi[RP_OUT + n + 1];
    for (int p = o0; p < o1; p++) {
        const unsigned* s = f9o + (size_t)p * 8;
        uint4 a = *(const uint4*)s;
        unsigned e8 = s[4];
        agg[0] -= blo(a.x); agg[1] -= bhi(a.x);
        agg[2] -= blo(a.y); agg[3] -= bhi(a.y);
        agg[4] -= blo(a.z); agg[5] -= bhi(a.z);
        agg[6] -= blo(a.w); agg[7] -= bhi(a.w);
        agg[8] -= blo(e8);
    }
    gru_core3(wsf, feature, out, t, lane, q, g, b, n, agg);
}

__global__ __launch_bounds__(256) void k_gru3(float* wsf, const void* feature, void* out, int t)
{
    const int* wsi = (const int*)wsf;
    if (wsf[IDX_FLAG] > 0.5f) gru3_body(wsf, wsi, (const bf16*)feature, (bf16*)out, t);
    else                      gru3_body(wsf, wsi, (const float*)feature, (float*)out, t);
}

extern "C" void kernel_launch(void* const* d_in, const int* in_sizes, int n_in,
                              void* d_out, int out_size, void* d_ws, size_t ws_size,
                              hipStream_t stream)
{
    float* wsf = (float*)d_ws;
    int*   wsi = (int*)d_ws;
    const void* rain    = d_in[0];
    const void* feature = d_in[1];
    const int*  eidx    = (const int*)d_in[2];
    const void* ea      = d_in[3];
    const void* wm      = d_in[4];
    const void* wsd     = d_in[5];

    bool fast2 = (ws_size >= NEW_WS_BYTES);
    bool fast  = (ws_size >= FAST_WS_BYTES);

    hipMemsetAsync(wsf, 0, 16 * sizeof(float), stream);
    hipMemsetAsync(wsf + OFF_H, 0, (size_t)BN * NNODE * HID * sizeof(float), stream);

    k_sniff<<<1, 64, 0, stream>>>(wsf, ea);
    k_weights<<<(W_TOTAL + 255) / 256, 256, 0, stream>>>(wsf,
        d_in[6], d_in[7], d_in[8], d_in[9], d_in[10], d_in[11], d_in[12],
        d_in[13], d_in[14], d_in[15], d_in[16], d_in[17], wm, wsd);
    k_stats<<<NEDGE / 256, 256, 0, stream>>>(wsf, ea);
    k_init<<<(BN * NNODE + 255) / 256, 256, 0, stream>>>(wsf, rain);

    if (fast2 || fast) {
        hipMemsetAsync(wsi + RP_IN, 0, 20032 * sizeof(int), stream);
        k_csr_hist<<<NEDGE / 256, 256, 0, stream>>>(wsi, eidx);
        k_csr_scan<<<2, 256, 0, stream>>>(wsi);
        k_csr_fill<<<NEDGE / 256, 256, 0, stream>>>(wsi, eidx);
    }

    if (fast2) {
        for (int t = 0; t < PRED; t++) {
            dim3 gn((NNODE + 255) / 256, BN);
            k_node<<<gn, 256, 0, stream>>>(wsf, feature, t);
            dim3 ge(NEDGE / 256, BN);
            k_edge3<<<ge, 256, 0, stream>>>(wsf, eidx, ea, t);
            k_gru3<<<(BN * NNODE) / 64, 256, 0, stream>>>(wsf, feature, d_out, t);
        }
    } else if (fast) {
        for (int t = 0; t < PRED; t++) {
            dim3 ge(NEDGE / 256, BN);
            k_edge2<<<ge, 256, 0, stream>>>(wsf, eidx, ea, feature, t);
            k_gru2<<<(BN * NNODE) / 64, 256, 0, stream>>>(wsf, feature, d_out, t);
        }
    } else {
        for (int t = 0; t < PRED; t++) {
            hipMemsetAsync(wsf + OFF_AGG, 0, (size_t)BN * NNODE * GOUT * sizeof(float), stream);
            dim3 ge(NEDGE / 256, BN);
            k_edge<<<ge, 256, 0, stream>>>(wsf, eidx, ea, feature, t);
            k_gru<<<(BN * NNODE) / 64, 256, 0, stream>>>(wsf, feature, d_out, t);
        }
    }
}

// Round 5
// 3667.818 us; speedup vs baseline: 2.8897x; 1.0192x over previous
//
#include <hip/hip_runtime.h>
#include <hip/hip_bf16.h>

typedef __hip_bfloat16 bf16;

#define BN    4
#define HIST  24
#define PRED  12
#define NNODE 10000
#define NEDGE 160000
#define FEAT  31
#define TSTEPS 36
#define EH    32
#define EOUT  30
#define GOUT  9
#define HID   64

#define IDX_FLAG 4
#define OFF_W    16
#define W_WE1   0
#define W_BE1   2144
#define W_WE2T  2176
#define W_BE2   3136
#define W_WN    3166
#define W_BN    3436
#define W_WIHT  3445
#define W_BIH   11317
#define W_WHHT  11509
#define W_BHH   23797
#define W_WOUT  23989
#define W_BOUT  24053
#define W_WM    24054
#define W_WSD   24056
#define W_TOTAL 24058

#define OFF_XN  24096
#define OFF_AGG 64096
#define OFF_H   424096
#define OFF_CSR 2984096
#define RP_IN   (OFF_CSR)
#define RP_OUT  (OFF_CSR + 10016)
#define CUR_IN  (OFF_CSR + 20032)
#define CUR_OUT (OFF_CSR + 30048)
#define PERM_IN (OFF_CSR + 40064)
#define PERM_OUT (OFF_CSR + 200064)
#define OFF_F9  3344160
#define FAST_WS_FLOATS 11024160ull
#define FAST_WS_BYTES  (FAST_WS_FLOATS * 4ull)
#define IPOS_IN  3344160
#define IPOS_OUT 3504160
#define OFF_PST  3664160
#define OFF_WIND 6224160
#define OFF_F9I  6304160
#define OFF_F9O  11424160
#define NEW_WS_FLOATS 16544160ull
#define NEW_WS_BYTES (NEW_WS_FLOATS * 4ull)

__device__ __forceinline__ float cvt(bf16 v)  { return __bfloat162float(v); }
__device__ __forceinline__ float cvt(float v) { return v; }
__device__ __forceinline__ float sigm(float x){ return 1.0f / (1.0f + __expf(-x)); }
__device__ __forceinline__ unsigned f2b1(float x){
    unsigned u = __float_as_uint(x);
    return (u + 0x7fffu + ((u >> 16) & 1u)) >> 16;
}
__device__ __forceinline__ float blo(unsigned u){ return __uint_as_float(u << 16); }
__device__ __forceinline__ float bhi(unsigned u){ return __uint_as_float(u & 0xffff0000u); }

__global__ void k_sniff(float* __restrict__ wsf, const void* __restrict__ ea)
{
    const bf16* p = (const bf16*)ea;
    int lane = threadIdx.x;
    float v = __bfloat162float(p[2 * lane]);
    bool ok = (v >= 0.03f) && (v <= 1.3f);
    unsigned long long m = __ballot(ok);
    if (lane == 0) wsf[IDX_FLAG] = (m == ~0ull) ? 1.0f : 0.0f;
}

template<typename T>
__device__ __forceinline__ void weights_body(float* W,
    const T* We1, const T* be1, const T* We2, const T* be2,
    const T* Wn,  const T* bn,  const T* Wih, const T* bih,
    const T* Whh, const T* bhh, const T* Wout, const T* bout,
    const T* wm,  const T* wsd)
{
    int r = blockIdx.x * blockDim.x + threadIdx.x;
    if (r < 2144) { W[W_WE1 + r] = cvt(We1[r]); return; } r -= 2144;
    if (r < 32)   { W[W_BE1 + r] = cvt(be1[r]); return; } r -= 32;
    if (r < 960)  { int k = r / 32, j = r % 32; W[W_WE2T + r] = cvt(We2[j*30 + k]); return; } r -= 960;
    if (r < 30)   { W[W_BE2 + r] = cvt(be2[r]); return; } r -= 30;
    if (r < 270)  { W[W_WN  + r] = cvt(Wn[r]);  return; } r -= 270;
    if (r < 9)    { W[W_BN  + r] = cvt(bn[r]);  return; } r -= 9;
    if (r < 7872) { int row = r / 41, i = r % 41; W[W_WIHT + r] = cvt(Wih[i*192 + row]); return; } r -= 7872;
    if (r < 192)  { W[W_BIH + r] = cvt(bih[r]); return; } r -= 192;
    if (r < 12288){ int row = r / 64, i = r % 64; W[W_WHHT + r] = cvt(Whh[i*192 + row]); return; } r -= 12288;
    if (r < 192)  { W[W_BHH + r] = cvt(bhh[r]); return; } r -= 192;
    if (r < 64)   { W[W_WOUT + r] = cvt(Wout[r]); return; } r -= 64;
    if (r < 1)    { W[W_BOUT] = cvt(bout[0]); return; } r -= 1;
    if (r < 2)    { W[W_WM + r] = cvt(wm[r]); return; } r -= 2;
    if (r < 2)    { W[W_WSD + r] = cvt(wsd[r]); return; }
}

__global__ void k_weights(float* wsf,
    const void* We1, const void* be1, const void* We2, const void* be2,
    const void* Wn,  const void* bn,  const void* Wih, const void* bih,
    const void* Whh, const void* bhh, const void* Wout, const void* bout,
    const void* wm,  const void* wsd)
{
    float* W = wsf + OFF_W;
    if (wsf[IDX_FLAG] > 0.5f)
        weights_body(W, (const bf16*)We1, (const bf16*)be1, (const bf16*)We2, (const bf16*)be2,
                        (const bf16*)Wn,  (const bf16*)bn,  (const bf16*)Wih, (const bf16*)bih,
                        (const bf16*)Whh, (const bf16*)bhh, (const bf16*)Wout, (const bf16*)bout,
                        (const bf16*)wm,  (const bf16*)wsd);
    else
        weights_body(W, (const float*)We1, (const float*)be1, (const float*)We2, (const float*)be2,
                        (const float*)Wn,  (const float*)bn,  (const float*)Wih, (const float*)bih,
                        (const float*)Whh, (const float*)bhh, (const float*)Wout, (const float*)bout,
                        (const float*)wm,  (const float*)wsd);
}

template<typename T>
__device__ __forceinline__ void stats_body(float* wsf, const T* ea)
{
    int e = blockIdx.x * 256 + threadIdx.x;
    float d = cvt(ea[2*e]), c = cvt(ea[2*e + 1]);
    float v0 = d, v1 = c, v2 = d*d, v3 = c*c;
    #pragma unroll
    for (int o = 32; o > 0; o >>= 1) {
        v0 += __shfl_down(v0, o);
        v1 += __shfl_down(v1, o);
        v2 += __shfl_down(v2, o);
        v3 += __shfl_down(v3, o);
    }
    if ((threadIdx.x & 63) == 0) {
        unsafeAtomicAdd(&wsf[0], v0);
        unsafeAtomicAdd(&wsf[1], v1);
        unsafeAtomicAdd(&wsf[2], v2);
        unsafeAtomicAdd(&wsf[3], v3);
    }
}

__global__ __launch_bounds__(256) void k_stats(float* wsf, const void* ea)
{
    if (wsf[IDX_FLAG] > 0.5f) stats_body(wsf, (const bf16*)ea);
    else                      stats_body(wsf, (const float*)ea);
}

template<typename T>
__device__ __forceinline__ void init_body(float* wsf, const T* rain)
{
    int g = blockIdx.x * blockDim.x + threadIdx.x;
    if (g >= BN * NNODE) return;
    int b = g / NNODE, n = g % NNODE;
    wsf[OFF_XN + g] = cvt(rain[(b * HIST + (HIST - 1)) * NNODE + n]);
}

__global__ void k_init(float* wsf, const void* rain)
{
    if (wsf[IDX_FLAG] > 0.5f) init_body(wsf, (const bf16*)rain);
    else                      init_body(wsf, (const float*)rain);
}

__global__ __launch_bounds__(256) void k_csr_hist(int* wsi, const int* __restrict__ eidx)
{
    int e = blockIdx.x * 256 + threadIdx.x;
    atomicAdd(&wsi[RP_IN  + eidx[NEDGE + e]], 1);
    atomicAdd(&wsi[RP_OUT + eidx[e]],         1);
}

__global__ __launch_bounds__(256) void k_csr_scan(int* wsi)
{
    int* arr = (blockIdx.x == 0) ? (wsi + RP_IN)  : (wsi + RP_OUT);
    int* cur = (blockIdx.x == 0) ? (wsi + CUR_IN) : (wsi + CUR_OUT);
    __shared__ int tot[256], base[256];
    const int CH = 40;
    int tid = threadIdx.x, st = tid * CH;
    int loc[CH];
    int s = 0;
    #pragma unroll
    for (int i = 0; i < CH; i++) {
        int idx = st + i;
        int v = (idx < NNODE) ? arr[idx] : 0;
        loc[i] = s; s += v;
    }
    tot[tid] = s;
    __syncthreads();
    if (tid == 0) {
        int r = 0;
        for (int i = 0; i < 256; i++) { base[i] = r; r += tot[i]; }
        arr[NNODE] = r;
    }
    __syncthreads();
    int b = base[tid];
    #pragma unroll
    for (int i = 0; i < CH; i++) {
        int idx = st + i;
        if (idx < NNODE) { int v = b + loc[i]; arr[idx] = v; cur[idx] = v; }
    }
}

__global__ __launch_bounds__(256) void k_csr_fill(int* wsi, const int* __restrict__ eidx)
{
    int e = blockIdx.x * 256 + threadIdx.x;
    int src = eidx[e], tgt = eidx[NEDGE + e];
    int p = atomicAdd(&wsi[CUR_IN  + tgt], 1);
    wsi[PERM_IN + p] = e;
    wsi[IPOS_IN + e] = p;
    int q = atomicAdd(&wsi[CUR_OUT + src], 1);
    wsi[PERM_OUT + q] = e;
    wsi[IPOS_OUT + e] = q;
}

template<typename T>
__device__ __forceinline__ void edge_mlp(float* wsf, const int* eidx,
                                         const T* ea, const T* feature,
                                         int e, int b, int t, float f9[GOUT])
{
    const float* W = wsf + OFF_W;
    int src = eidx[e], tgt = eidx[NEDGE + e];

    const float invE = 1.0f / (float)NEDGE;
    float s0 = wsf[0], s1 = wsf[1], q0 = wsf[2], q1 = wsf[3];
    float m0 = s0 * invE, m1 = s1 * invE;
    float istd0 = rsqrtf(fmaxf((q0 - s0 * m0) * (1.0f / (NEDGE - 1)), 1e-20f));
    float istd1 = rsqrtf(fmaxf((q1 - s1 * m1) * (1.0f / (NEDGE - 1)), 1e-20f));

    float dist = cvt(ea[2*e]), cdir = cvt(ea[2*e + 1]);
    float ean0 = (dist - m0) * istd0, ean1 = (cdir - m1) * istd1;

    size_t frow = (size_t)(b * TSTEPS + HIST + t) * NNODE;
    const T* fS = feature + (frow + src) * FEAT;
    const T* fT = feature + (frow + tgt) * FEAT;
    float xnS = wsf[OFF_XN + b * NNODE + src];
    float xnT = wsf[OFF_XN + b * NNODE + tgt];

    float speed = cvt(fS[29]) * W[W_WSD + 0] + W[W_WM + 0];
    float direc = cvt(fS[30]) * W[W_WSD + 1] + W[W_WM + 1];
    float theta = fabsf(cdir - direc);
    float ew = fmaxf(3.0f * speed * cosf(theta * 22.5f) / dist, 0.0f);

    const float* We1 = W + W_WE1;
    float acc[EH];
    #pragma unroll
    for (int j = 0; j < EH; j++)
        acc[j] = W[W_BE1 + j] + xnS * We1[j] + xnT * We1[32*EH + j]
               + ean0 * We1[64*EH + j] + ean1 * We1[65*EH + j] + ew * We1[66*EH + j];
    for (int i = 0; i < FEAT; i++) {
        float v = cvt(fS[i]);
        const float* wr = We1 + (1 + i) * EH;
        #pragma unroll
        for (int j = 0; j < EH; j++) acc[j] += v * wr[j];
    }
    for (int i = 0; i < FEAT; i++) {
        float v = cvt(fT[i]);
        const float* wr = We1 + (33 + i) * EH;
        #pragma unroll
        for (int j = 0; j < EH; j++) acc[j] += v * wr[j];
    }
    #pragma unroll
    for (int j = 0; j < EH; j++) acc[j] = sigm(acc[j]);

    #pragma unroll
    for (int m = 0; m < GOUT; m++) f9[m] = 0.0f;
    const float* We2T = W + W_WE2T;
    const float* WnW  = W + W_WN;
    for (int k = 0; k < EOUT; k++) {
        float a = W[W_BE2 + k];
        const float* wr = We2T + k * EH;
        #pragma unroll
        for (int j = 0; j < EH; j++) a += acc[j] * wr[j];
        float ek = sigm(a);
        const float* wn = WnW + k * GOUT;
        #pragma unroll
        for (int m = 0; m < GOUT; m++) f9[m] += ek * wn[m];
    }
}

template<typename T>
__device__ __forceinline__ void edge_body(float* wsf, const int* eidx,
                                          const T* ea, const T* feature, int t)
{
    int e = blockIdx.x * 256 + threadIdx.x;
    int b = blockIdx.y;
    float f9[GOUT];
    edge_mlp(wsf, eidx, ea, feature, e, b, t, f9);
    int src = eidx[e], tgt = eidx[NEDGE + e];
    float* aggT = wsf + OFF_AGG + (size_t)(b * NNODE + tgt) * GOUT;
    float* aggS = wsf + OFF_AGG + (size_t)(b * NNODE + src) * GOUT;
    #pragma unroll
    for (int m = 0; m < GOUT; m++) {
        unsafeAtomicAdd(&aggT[m],  f9[m]);
        unsafeAtomicAdd(&aggS[m], -f9[m]);
    }
}

__global__ __launch_bounds__(256) void k_edge(float* wsf, const int* eidx,
                                              const void* ea, const void* feature, int t)
{
    if (wsf[IDX_FLAG] > 0.5f) edge_body(wsf, eidx, (const bf16*)ea, (const bf16*)feature, t);
    else                      edge_body(wsf, eidx, (const float*)ea, (const float*)feature, t);
}

template<typename T>
__device__ __forceinline__ void edge2_body(float* wsf, const int* eidx,
                                           const T* ea, const T* feature, int t)
{
    int e = blockIdx.x * 256 + threadIdx.x;
    int b = blockIdx.y;
    float f9[GOUT];
    edge_mlp(wsf, eidx, ea, feature, e, b, t, f9);
    float4* p = (float4*)(wsf + OFF_F9 + (size_t)(b * NEDGE + e) * 12);
    p[0] = make_float4(f9[0], f9[1], f9[2], f9[3]);
    p[1] = make_float4(f9[4], f9[5], f9[6], f9[7]);
    p[2] = make_float4(f9[8], 0.0f, 0.0f, 0.0f);
}

__global__ __launch_bounds__(256) void k_edge2(float* wsf, const int* eidx,
                                               const void* ea, const void* feature, int t)
{
    if (wsf[IDX_FLAG] > 0.5f) edge2_body(wsf, eidx, (const bf16*)ea, (const bf16*)feature, t);
    else                      edge2_body(wsf, eidx, (const float*)ea, (const float*)feature, t);
}

// ---- per-node precompute pS/pT + wind ----
template<typename T>
__device__ __forceinline__ void node_body(float* wsf, const T* feature, int t, uint4* sfeat)
{
    int tid = threadIdx.x;
    int base = blockIdx.x * 256;
    int b = blockIdx.y;
    int n = base + tid;
    size_t frow = (size_t)(b * TSTEPS + HIST + t) * NNODE;
    const int rowB = FEAT * (int)sizeof(T);
    int nvalid = min(256, NNODE - base);
    int vbytes = nvalid * rowB;

    const uint4* gsrc = (const uint4*)((const char*)feature + (frow + base) * rowB);
    for (int c = tid; c * 16 < vbytes; c += 256) sfeat[c] = gsrc[c];
    __syncthreads();
    if (n >= NNODE) return;

    const T* srow = (const T*)((const char*)sfeat + (size_t)tid * rowB);
    float x[32];
    x[0] = wsf[OFF_XN + b * NNODE + n];
    #pragma unroll
    for (int i = 0; i < FEAT; i++) x[1 + i] = cvt(srow[i]);

    const float* W = wsf + OFF_W;
    float acc[64];
    #pragma unroll
    for (int j = 0; j < 32; j++) acc[j] = W[W_BE1 + j];
    #pragma unroll
    for (int j = 0; j < 32; j++) acc[32 + j] = 0.0f;
    #pragma unroll
    for (int i = 0; i < 32; i++) {
        float v = x[i];
        const float* wS = W + W_WE1 + i * EH;
        const float* wT = W + W_WE1 + (32 + i) * EH;
        #pragma unroll
        for (int j = 0; j < 32; j++) { acc[j] += v * wS[j]; acc[32 + j] += v * wT[j]; }
    }

    float4* prow = (float4*)(wsf + OFF_PST + (size_t)(b * NNODE + n) * 64);
    #pragma unroll
    for (int jv = 0; jv < 16; jv++)
        prow[jv] = make_float4(acc[jv*4], acc[jv*4+1], acc[jv*4+2], acc[jv*4+3]);

    float speed = x[30] * W[W_WSD + 0] + W[W_WM + 0];
    float direc = x[31] * W[W_WSD + 1] + W[W_WM + 1];
    ((float2*)(wsf + OFF_WIND))[b * NNODE + n] = make_float2(speed, direc);
}

__global__ __launch_bounds__(256) void k_node(float* wsf, const void* feature, int t)
{
    __shared__ uint4 sfeat[1984];
    if (wsf[IDX_FLAG] > 0.5f) node_body(wsf, (const bf16*)feature, t, sfeat);
    else                      node_body(wsf, (const float*)feature, t, sfeat);
}

// ---- edge kernel: from pS/pT, bf16 f9 stores into CSR-ordered slots ----
template<typename T>
__device__ __forceinline__ void edge3_body(float* wsf, const int* wsi, const int* eidx,
                                           const T* ea, int t)
{
    int e = blockIdx.x * 256 + threadIdx.x;
    int b = blockIdx.y;
    const float* W = wsf + OFF_W;

    int src = eidx[e], tgt = eidx[NEDGE + e];
    int ipi = wsi[IPOS_IN + e], ipo = wsi[IPOS_OUT + e];

    const float invE = 1.0f / (float)NEDGE;
    float s0 = wsf[0], s1 = wsf[1], q0 = wsf[2], q1 = wsf[3];
    float m0 = s0 * invE, m1 = s1 * invE;
    float istd0 = rsqrtf(fmaxf((q0 - s0 * m0) * (1.0f / (NEDGE - 1)), 1e-20f));
    float istd1 = rsqrtf(fmaxf((q1 - s1 * m1) * (1.0f / (NEDGE - 1)), 1e-20f));

    float dist = cvt(ea[2*e]), cdir = cvt(ea[2*e + 1]);
    float ean0 = (dist - m0) * istd0, ean1 = (cdir - m1) * istd1;

    float2 wv = ((const float2*)(wsf + OFF_WIND))[b * NNODE + src];
    float theta = fabsf(cdir - wv.y);
    float ew = fmaxf(3.0f * wv.x * cosf(theta * 22.5f) / dist, 0.0f);

    const float4* ps4 = (const float4*)(wsf + OFF_PST + (size_t)(b * NNODE + src) * 64);
    const float4* pt4 = (const float4*)(wsf + OFF_PST + (size_t)(b * NNODE + tgt) * 64) + 8;

    float l1[EH];
    #pragma unroll
    for (int jv = 0; jv < 8; jv++) {
        float4 a = ps4[jv], c = pt4[jv];
        l1[jv*4+0] = a.x + c.x; l1[jv*4+1] = a.y + c.y;
        l1[jv*4+2] = a.z + c.z; l1[jv*4+3] = a.w + c.w;
    }
    const float* w64 = W + W_WE1 + 64*EH;
    const float* w65 = W + W_WE1 + 65*EH;
    const float* w66 = W + W_WE1 + 66*EH;
    #pragma unroll
    for (int j = 0; j < EH; j++)
        l1[j] = sigm(l1[j] + ean0 * w64[j] + ean1 * w65[j] + ew * w66[j]);

    float f9[GOUT];
    #pragma unroll
    for (int m = 0; m < GOUT; m++) f9[m] = 0.0f;
    const float* We2T = W + W_WE2T;
    const float* WnW  = W + W_WN;
    for (int k = 0; k < EOUT; k++) {
        float a = W[W_BE2 + k];
        const float* wr = We2T + k * EH;
        #pragma unroll
        for (int j = 0; j < EH; j++) a += l1[j] * wr[j];
        float ek = sigm(a);
        const float* wn = WnW + k * GOUT;
        #pragma unroll
        for (int m = 0; m < GOUT; m++) f9[m] += ek * wn[m];
    }

    unsigned u0 = f2b1(f9[0]) | (f2b1(f9[1]) << 16);
    unsigned u1 = f2b1(f9[2]) | (f2b1(f9[3]) << 16);
    unsigned u2 = f2b1(f9[4]) | (f2b1(f9[5]) << 16);
    unsigned u3 = f2b1(f9[6]) | (f2b1(f9[7]) << 16);
    unsigned u4 = f2b1(f9[8]);

    unsigned* pi = (unsigned*)(wsf + OFF_F9I) + ((size_t)b * NEDGE + ipi) * 8;
    ((uint4*)pi)[0] = make_uint4(u0, u1, u2, u3);
    pi[4] = u4;
    unsigned* po = (unsigned*)(wsf + OFF_F9O) + ((size_t)b * NEDGE + ipo) * 8;
    ((uint4*)po)[0] = make_uint4(u0, u1, u2, u3);
    po[4] = u4;
}

__global__ __launch_bounds__(256) void k_edge3(float* wsf, const int* eidx,
                                               const void* ea, int t)
{
    const int* wsi = (const int*)wsf;
    if (wsf[IDX_FLAG] > 0.5f) edge3_body(wsf, wsi, eidx, (const bf16*)ea, t);
    else                      edge3_body(wsf, wsi, eidx, (const float*)ea, t);
}

// ---- GRU core (R2/R3 fallback) ----
template<typename T, typename OT>
__device__ __forceinline__ void gru_core(float* wsf, const T* feature, OT* out, int t,
                                         int lane, int q, int g, int b, int n,
                                         const float agg[GOUT])
{
    __shared__ float lpx[4][64];
    const float* W = wsf + OFF_W;

    float xc[41];
    #pragma unroll
    for (int m = 0; m < GOUT; m++) xc[m] = sigm(agg[m] + W[W_BN + m]);
    xc[9] = wsf[OFF_XN + g];
    const T* fp = feature + ((size_t)(b * TSTEPS + HIST + t) * NNODE + n) * FEAT;
    #pragma unroll
    for (int i = 0; i < FEAT; i++) xc[10 + i] = cvt(fp[i]);

    float* hbuf = wsf + OFF_H + (size_t)g * HID;
    float h[HID];
    #pragma unroll
    for (int i = 0; i < HID; i++) h[i] = hbuf[i];
    float hmine[16];
    #pragma unroll
    for (int jj = 0; jj < 16; jj++) hmine[jj] = hbuf[(q << 4) + jj];

    __syncthreads();

    float px = 0.0f;
    for (int jj = 0; jj < 16; jj++) {
        int j = (q << 4) + jj;
        const float* wr = W + W_WIHT + j * 41;
        const float* wz = W + W_WIHT + (64 + j) * 41;
        const float* wg = W + W_WIHT + (128 + j) * 41;
        float ir = W[W_BIH + j], iz = W[W_BIH + 64 + j], ig = W[W_BIH + 128 + j];
        #pragma unroll
        for (int i = 0; i < 41; i++) {
            ir += xc[i] * wr[i]; iz += xc[i] * wz[i]; ig += xc[i] * wg[i];
        }
        const float* vr = W + W_WHHT + j * 64;
        const float* vz = W + W_WHHT + (64 + j) * 64;
        const float* vg = W + W_WHHT + (128 + j) * 64;
        float hr = W[W_BHH + j], hz = W[W_BHH + 64 + j], hg = W[W_BHH + 128 + j];
        #pragma unroll
        for (int i = 0; i < HID; i++) {
            hr += h[i] * vr[i]; hz += h[i] * vz[i]; hg += h[i] * vg[i];
        }
        float r  = sigm(ir + hr);
        float z  = sigm(iz + hz);
        float nn = tanhf(ig + r * hg);
        float hnew = (1.0f - z) * nn + z * hmine[jj];
        hbuf[j] = hnew;
        px += hnew * W[W_WOUT + j];
    }
    lpx[q][lane] = px;
    __syncthreads();
    if (q == 0) {
        float v = lpx[0][lane] + lpx[1][lane] + lpx[2][lane] + lpx[3][lane] + W[W_BOUT];
        wsf[OFF_XN + g] = v;
        out[((size_t)b * PRED + t) * NNODE + n] = (OT)v;
    }
}

template<typename T, typename OT>
__device__ __forceinline__ void gru_body(float* wsf, const T* feature, OT* out, int t)
{
    int lane = threadIdx.x & 63, q = threadIdx.x >> 6;
    int g = blockIdx.x * 64 + lane;
    int b = g / NNODE, n = g % NNODE;
    float agg[GOUT];
    const float* ap = wsf + OFF_AGG + (size_t)g * GOUT;
    #pragma unroll
    for (int m = 0; m < GOUT; m++) agg[m] = ap[m];
    gru_core(wsf, feature, out, t, lane, q, g, b, n, agg);
}

__global__ __launch_bounds__(256) void k_gru(float* wsf, const void* feature, void* out, int t)
{
    if (wsf[IDX_FLAG] > 0.5f) gru_body(wsf, (const bf16*)feature, (bf16*)out, t);
    else                      gru_body(wsf, (const float*)feature, (float*)out, t);
}

template<typename T, typename OT>
__device__ __forceinline__ void gru2_body(float* wsf, const int* wsi, const T* feature, OT* out, int t)
{
    int lane = threadIdx.x & 63, q = threadIdx.x >> 6;
    int g = blockIdx.x * 64 + lane;
    int b = g / NNODE, n = g % NNODE;

    const float* F9b = wsf + OFF_F9 + (size_t)b * NEDGE * 12;
    float agg[GOUT];
    #pragma unroll
    for (int m = 0; m < GOUT; m++) agg[m] = 0.0f;

    int i0 = wsi[RP_IN + n], i1 = wsi[RP_IN + n + 1];
    for (int i = i0; i < i1; i++) {
        int e = wsi[PERM_IN + i];
        const float4* p = (const float4*)(F9b + (size_t)e * 12);
        float4 a = p[0], c = p[1], d = p[2];
        agg[0] += a.x; agg[1] += a.y; agg[2] += a.z; agg[3] += a.w;
        agg[4] += c.x; agg[5] += c.y; agg[6] += c.z; agg[7] += c.w;
        agg[8] += d.x;
    }
    int o0 = wsi[RP_OUT + n], o1 = wsi[RP_OUT + n + 1];
    for (int i = o0; i < o1; i++) {
        int e = wsi[PERM_OUT + i];
        const float4* p = (const float4*)(F9b + (size_t)e * 12);
        float4 a = p[0], c = p[1], d = p[2];
        agg[0] -= a.x; agg[1] -= a.y; agg[2] -= a.z; agg[3] -= a.w;
        agg[4] -= c.x; agg[5] -= c.y; agg[6] -= c.z; agg[7] -= c.w;
        agg[8] -= d.x;
    }
    gru_core(wsf, feature, out, t, lane, q, g, b, n, agg);
}

__global__ __launch_bounds__(256) void k_gru2(float* wsf, const void* feature, void* out, int t)
{
    const int* wsi = (const int*)wsf;
    if (wsf[IDX_FLAG] > 0.5f) gru2_body(wsf, wsi, (const bf16*)feature, (bf16*)out, t);
    else                      gru2_body(wsf, wsi, (const float*)feature, (float*)out, t);
}

// ---- NEW GRU: all node state in LDS; weights uniform (SGPR); coalesced block-transposed H ----
// LDS xch[i][node]: i 0..8 gnn-sigmoid, 9 xn, 10..40 feat, 41..104 h_old
template<typename T, typename OT>
__device__ __forceinline__ void gru4_body(float* wsf, const int* wsi, const T* feature, OT* out, int t,
                                          float* xch, float* part, float* lpx)
{
    int tid = threadIdx.x;
    int lane = tid & 63, q = tid >> 6;
    int g = blockIdx.x * 64 + lane;
    int b = g / NNODE, n = g % NNODE;
    const float* W = wsf + OFF_W;

    // ---- gather partials: wave q takes a contiguous quarter of each list ----
    float agg[GOUT];
    #pragma unroll
    for (int m = 0; m < GOUT; m++) agg[m] = 0.0f;
    {
        const unsigned* f9i = (const unsigned*)(wsf + OFF_F9I) + (size_t)b * NEDGE * 8;
        int i0 = wsi[RP_IN + n], i1 = wsi[RP_IN + n + 1];
        int ch = (i1 - i0 + 3) >> 2;
        int p0 = i0 + q * ch, p1 = min(p0 + ch, i1);
        for (int p = p0; p < p1; p++) {
            const unsigned* s = f9i + (size_t)p * 8;
            uint4 a = *(const uint4*)s; unsigned e8 = s[4];
            agg[0] += blo(a.x); agg[1] += bhi(a.x);
            agg[2] += blo(a.y); agg[3] += bhi(a.y);
            agg[4] += blo(a.z); agg[5] += bhi(a.z);
            agg[6] += blo(a.w); agg[7] += bhi(a.w);
            agg[8] += blo(e8);
        }
        const unsigned* f9o = (const unsigned*)(wsf + OFF_F9O) + (size_t)b * NEDGE * 8;
        int o0 = wsi[RP_OUT + n], o1 = wsi[RP_OUT + n + 1];
        ch = (o1 - o0 + 3) >> 2;
        p0 = o0 + q * ch; p1 = min(p0 + ch, o1);
        for (int p = p0; p < p1; p++) {
            const unsigned* s = f9o + (size_t)p * 8;
            uint4 a = *(const uint4*)s; unsigned e8 = s[4];
            agg[0] -= blo(a.x); agg[1] -= bhi(a.x);
            agg[2] -= blo(a.y); agg[3] -= bhi(a.y);
            agg[4] -= blo(a.z); agg[5] -= bhi(a.z);
            agg[6] -= blo(a.w); agg[7] -= bhi(a.w);
            agg[8] -= blo(e8);
        }
    }
    #pragma unroll
    for (int m = 0; m < GOUT; m++) part[(q * 64 + lane) * GOUT + m] = agg[m];

    // ---- fill h rows (coalesced) and feature rows ----
    float* Ht = wsf + OFF_H + (size_t)blockIdx.x * (64 * 64);
    #pragma unroll
    for (int k = 0; k < 16; k++) {
        int i = k * 4 + q;
        xch[(41 + i) * 64 + lane] = Ht[i * 64 + lane];
    }
    {
        size_t frow = (size_t)(b * TSTEPS + HIST + t) * NNODE;
        const T* fp = feature + (frow + n) * FEAT;
        for (int i = 10 + q; i < 41; i += 4)
            xch[i * 64 + lane] = cvt(fp[i - 10]);
    }
    __syncthreads();

    if (q == 0) {
        #pragma unroll
        for (int m = 0; m < GOUT; m++) {
            float s = part[(0 * 64 + lane) * GOUT + m] + part[(1 * 64 + lane) * GOUT + m]
                    + part[(2 * 64 + lane) * GOUT + m] + part[(3 * 64 + lane) * GOUT + m];
            xch[m * 64 + lane] = sigm(s + W[W_BN + m]);
        }
        xch[9 * 64 + lane] = wsf[OFF_XN + g];
    }
    __syncthreads();

    // ---- compute: wave q -> j in [16q, 16q+16), 4 at a time; weights via SGPR ----
    int jq = __builtin_amdgcn_readfirstlane(q);
    float px = 0.0f;
    #pragma unroll
    for (int jb = 0; jb < 4; jb++) {
        int j0 = jq * 16 + jb * 4;
        float ar[4], az[4], ag[4], ahg[4];
        #pragma unroll
        for (int u = 0; u < 4; u++) {
            ar[u]  = W[W_BIH + j0 + u] + W[W_BHH + j0 + u];
            az[u]  = W[W_BIH + 64 + j0 + u] + W[W_BHH + 64 + j0 + u];
            ag[u]  = W[W_BIH + 128 + j0 + u];
            ahg[u] = W[W_BHH + 128 + j0 + u];
        }
        for (int i = 0; i < 41; i++) {
            float v = xch[i * 64 + lane];
            #pragma unroll
            for (int u = 0; u < 4; u++) {
                ar[u] += v * W[W_WIHT + (j0 + u) * 41 + i];
                az[u] += v * W[W_WIHT + (64 + j0 + u) * 41 + i];
                ag[u] += v * W[W_WIHT + (128 + j0 + u) * 41 + i];
            }
        }
        for (int i = 0; i < 64; i++) {
            float v = xch[(41 + i) * 64 + lane];
            #pragma unroll
            for (int u = 0; u < 4; u++) {
                ar[u]  += v * W[W_WHHT + (j0 + u) * 64 + i];
                az[u]  += v * W[W_WHHT + (64 + j0 + u) * 64 + i];
                ahg[u] += v * W[W_WHHT + (128 + j0 + u) * 64 + i];
            }
        }
        #pragma unroll
        for (int u = 0; u < 4; u++) {
            float r  = sigm(ar[u]);
            float z  = sigm(az[u]);
            float nn = tanhf(ag[u] + r * ahg[u]);
            float hold = xch[(41 + j0 + u) * 64 + lane];
            float hnew = (1.0f - z) * nn + z * hold;
            Ht[(j0 + u) * 64 + lane] = hnew;           // coalesced 256B per j
            px += hnew * W[W_WOUT + j0 + u];
        }
    }
    lpx[q * 64 + lane] = px;
    __syncthreads();
    if (q == 0) {
        float v = lpx[lane] + lpx[64 + lane] + lpx[128 + lane] + lpx[192 + lane] + W[W_BOUT];
        wsf[OFF_XN + g] = v;
        out[((size_t)b * PRED + t) * NNODE + n] = (OT)v;
    }
}

__global__ __launch_bounds__(256) void k_gru4(float* wsf, const void* feature, void* out, int t)
{
    __shared__ float xch[105 * 64];     // 26.9 KB
    __shared__ float part[4 * 64 * GOUT]; // 9.2 KB
    __shared__ float lpx[4 * 64];       // 1 KB
    const int* wsi = (const int*)wsf;
    if (wsf[IDX_FLAG] > 0.5f) gru4_body(wsf, wsi, (const bf16*)feature, (bf16*)out, t, xch, part, lpx);
    else                      gru4_body(wsf, wsi, (const float*)feature, (float*)out, t, xch, part, lpx);
}

extern "C" void kernel_launch(void* const* d_in, const int* in_sizes, int n_in,
                              void* d_out, int out_size, void* d_ws, size_t ws_size,
                              hipStream_t stream)
{
    float* wsf = (float*)d_ws;
    int*   wsi = (int*)d_ws;
    const void* rain    = d_in[0];
    const void* feature = d_in[1];
    const int*  eidx    = (const int*)d_in[2];
    const void* ea      = d_in[3];
    const void* wm      = d_in[4];
    const void* wsd     = d_in[5];

    bool fast2 = (ws_size >= NEW_WS_BYTES);
    bool fast  = (ws_size >= FAST_WS_BYTES);

    hipMemsetAsync(wsf, 0, 16 * sizeof(float), stream);
    hipMemsetAsync(wsf + OFF_H, 0, (size_t)BN * NNODE * HID * sizeof(float), stream);

    k_sniff<<<1, 64, 0, stream>>>(wsf, ea);
    k_weights<<<(W_TOTAL + 255) / 256, 256, 0, stream>>>(wsf,
        d_in[6], d_in[7], d_in[8], d_in[9], d_in[10], d_in[11], d_in[12],
        d_in[13], d_in[14], d_in[15], d_in[16], d_in[17], wm, wsd);
    k_stats<<<NEDGE / 256, 256, 0, stream>>>(wsf, ea);
    k_init<<<(BN * NNODE + 255) / 256, 256, 0, stream>>>(wsf, rain);

    if (fast2 || fast) {
        hipMemsetAsync(wsi + RP_IN, 0, 20032 * sizeof(int), stream);
        k_csr_hist<<<NEDGE / 256, 256, 0, stream>>>(wsi, eidx);
        k_csr_scan<<<2, 256, 0, stream>>>(wsi);
        k_csr_fill<<<NEDGE / 256, 256, 0, stream>>>(wsi, eidx);
    }

    if (fast2) {
        for (int t = 0; t < PRED; t++) {
            dim3 gn((NNODE + 255) / 256, BN);
            k_node<<<gn, 256, 0, stream>>>(wsf, feature, t);
            dim3 ge(NEDGE / 256, BN);
            k_edge3<<<ge, 256, 0, stream>>>(wsf, eidx, ea, t);
            k_gru4<<<(BN * NNODE) / 64, 256, 0, stream>>>(wsf, feature, d_out, t);
        }
    } else if (fast) {
        for (int t = 0; t < PRED; t++) {
            dim3 ge(NEDGE / 256, BN);
            k_edge2<<<ge, 256, 0, stream>>>(wsf, eidx, ea, feature, t);
            k_gru2<<<(BN * NNODE) / 64, 256, 0, stream>>>(wsf, feature, d_out, t);
        }
    } else {
        for (int t = 0; t < PRED; t++) {
            hipMemsetAsync(wsf + OFF_AGG, 0, (size_t)BN * NNODE * GOUT * sizeof(float), stream);
            dim3 ge(NEDGE / 256, BN);
            k_edge<<<ge, 256, 0, stream>>>(wsf, eidx, ea, feature, t);
            k_gru<<<(BN * NNODE) / 64, 256, 0, stream>>>(wsf, feature, d_out, t);
        }
    }
}

// Round 6
// 2006.248 us; speedup vs baseline: 5.2829x; 1.8282x over previous
//
#include <hip/hip_runtime.h>
#include <hip/hip_bf16.h>

typedef __hip_bfloat16 bf16;
typedef __attribute__((ext_vector_type(8))) short bf16x8;
typedef __attribute__((ext_vector_type(4))) float f32x4;

#define BN    4
#define HIST  24
#define PRED  12
#define NNODE 10000
#define NEDGE 160000
#define FEAT  31
#define TSTEPS 36
#define EH    32
#define EOUT  30
#define GOUT  9
#define HID   64

#define IDX_FLAG 4
#define OFF_W    16
#define W_WE1   0
#define W_BE1   2144
#define W_WE2T  2176
#define W_BE2   3136
#define W_WN    3166
#define W_BN    3436
#define W_WIHT  3445
#define W_BIH   11317
#define W_WHHT  11509
#define W_BHH   23797
#define W_WOUT  23989
#define W_BOUT  24053
#define W_WM    24054
#define W_WSD   24056
#define W_TOTAL 24058

#define OFF_XN  24096
#define OFF_AGG 64096
#define OFF_H   424096
#define OFF_CSR 2984096
#define RP_IN   (OFF_CSR)
#define RP_OUT  (OFF_CSR + 10016)
#define CUR_IN  (OFF_CSR + 20032)
#define CUR_OUT (OFF_CSR + 30048)
#define PERM_IN (OFF_CSR + 40064)
#define PERM_OUT (OFF_CSR + 200064)
#define OFF_F9  3344160
#define FAST_WS_FLOATS 11024160ull
#define FAST_WS_BYTES  (FAST_WS_FLOATS * 4ull)
#define IPOS_IN  3344160
#define IPOS_OUT 3504160
#define OFF_PST  3664160
#define OFF_WIND 6224160
#define OFF_F9I  6304160
#define OFF_F9O  11424160
#define NEW_WS_FLOATS 16544160ull
#define NEW_WS_BYTES (NEW_WS_FLOATS * 4ull)
// ---- R6: MFMA GRU weight fragments (bf16, B-operand order) ----
#define WFRAG    16544160              // 32768 bf16 = 16384 floats
#define NEW3_WS_FLOATS (16544160ull + 16384ull)
#define NEW3_WS_BYTES (NEW3_WS_FLOATS * 4ull)   // 66.24 MB

__device__ __forceinline__ float cvt(bf16 v)  { return __bfloat162float(v); }
__device__ __forceinline__ float cvt(float v) { return v; }
__device__ __forceinline__ float sigm(float x){ return 1.0f / (1.0f + __expf(-x)); }
__device__ __forceinline__ unsigned f2b1(float x){
    unsigned u = __float_as_uint(x);
    return (u + 0x7fffu + ((u >> 16) & 1u)) >> 16;
}
__device__ __forceinline__ float blo(unsigned u){ return __uint_as_float(u << 16); }
__device__ __forceinline__ float bhi(unsigned u){ return __uint_as_float(u & 0xffff0000u); }

__global__ void k_sniff(float* __restrict__ wsf, const void* __restrict__ ea)
{
    const bf16* p = (const bf16*)ea;
    int lane = threadIdx.x;
    float v = __bfloat162float(p[2 * lane]);
    bool ok = (v >= 0.03f) && (v <= 1.3f);
    unsigned long long m = __ballot(ok);
    if (lane == 0) wsf[IDX_FLAG] = (m == ~0ull) ? 1.0f : 0.0f;
}

template<typename T>
__device__ __forceinline__ void weights_body(float* W,
    const T* We1, const T* be1, const T* We2, const T* be2,
    const T* Wn,  const T* bn,  const T* Wih, const T* bih,
    const T* Whh, const T* bhh, const T* Wout, const T* bout,
    const T* wm,  const T* wsd)
{
    int r = blockIdx.x * blockDim.x + threadIdx.x;
    if (r < 2144) { W[W_WE1 + r] = cvt(We1[r]); return; } r -= 2144;
    if (r < 32)   { W[W_BE1 + r] = cvt(be1[r]); return; } r -= 32;
    if (r < 960)  { int k = r / 32, j = r % 32; W[W_WE2T + r] = cvt(We2[j*30 + k]); return; } r -= 960;
    if (r < 30)   { W[W_BE2 + r] = cvt(be2[r]); return; } r -= 30;
    if (r < 270)  { W[W_WN  + r] = cvt(Wn[r]);  return; } r -= 270;
    if (r < 9)    { W[W_BN  + r] = cvt(bn[r]);  return; } r -= 9;
    if (r < 7872) { int row = r / 41, i = r % 41; W[W_WIHT + r] = cvt(Wih[i*192 + row]); return; } r -= 7872;
    if (r < 192)  { W[W_BIH + r] = cvt(bih[r]); return; } r -= 192;
    if (r < 12288){ int row = r / 64, i = r % 64; W[W_WHHT + r] = cvt(Whh[i*192 + row]); return; } r -= 12288;
    if (r < 192)  { W[W_BHH + r] = cvt(bhh[r]); return; } r -= 192;
    if (r < 64)   { W[W_WOUT + r] = cvt(Wout[r]); return; } r -= 64;
    if (r < 1)    { W[W_BOUT] = cvt(bout[0]); return; } r -= 1;
    if (r < 2)    { W[W_WM + r] = cvt(wm[r]); return; } r -= 2;
    if (r < 2)    { W[W_WSD + r] = cvt(wsd[r]); return; }
}

__global__ void k_weights(float* wsf,
    const void* We1, const void* be1, const void* We2, const void* be2,
    const void* Wn,  const void* bn,  const void* Wih, const void* bih,
    const void* Whh, const void* bhh, const void* Wout, const void* bout,
    const void* wm,  const void* wsd)
{
    float* W = wsf + OFF_W;
    if (wsf[IDX_FLAG] > 0.5f)
        weights_body(W, (const bf16*)We1, (const bf16*)be1, (const bf16*)We2, (const bf16*)be2,
                        (const bf16*)Wn,  (const bf16*)bn,  (const bf16*)Wih, (const bf16*)bih,
                        (const bf16*)Whh, (const bf16*)bhh, (const bf16*)Wout, (const bf16*)bout,
                        (const bf16*)wm,  (const bf16*)wsd);
    else
        weights_body(W, (const float*)We1, (const float*)be1, (const float*)We2, (const float*)be2,
                        (const float*)Wn,  (const float*)bn,  (const float*)Wih, (const float*)bih,
                        (const float*)Whh, (const float*)bhh, (const float*)Wout, (const float*)bout,
                        (const float*)wm,  (const float*)wsd);
}

// ---- build combined GRU weight Wc[128][256] in MFMA B-fragment order (bf16) ----
// xh rows k: 0..63 = h, 64..72 = gnn, 73 = xn, 74..104 = feat, 105..127 = 0
// cols n: 0..127 = r,z (Wih+Whh), 128..191 = ig (Wih only), 192..255 = hg (Whh only)
__global__ __launch_bounds__(256) void k_wfrag(float* wsf)
{
    int r = blockIdx.x * 256 + threadIdx.x;     // 32768 exact
    const float* W = wsf + OFF_W;
    int j  = r & 7;
    int L  = (r >> 3) & 63;
    int Kt = (r >> 9) & 3;
    int Nt = r >> 11;
    int k = Kt * 32 + ((L >> 4) & 3) * 8 + j;
    int n = Nt * 16 + (L & 15);
    float v = 0.0f;
    if (k < 64) {                                // h rows -> Whh[k][n]
        if (n < 128)      v = W[W_WHHT + n * 64 + k];
        else if (n >= 192) v = W[W_WHHT + (n - 64) * 64 + k];
    } else if (k < 105) {                        // xc rows -> Wih[k-64][n]
        int ix = k - 64;
        if (n < 192) v = W[W_WIHT + n * 41 + ix];
    }
    ((unsigned short*)(wsf + WFRAG))[((size_t)(Nt * 4 + Kt) * 64 + L) * 8 + j] = (unsigned short)f2b1(v);
}

template<typename T>
__device__ __forceinline__ void stats_body(float* wsf, const T* ea)
{
    int e = blockIdx.x * 256 + threadIdx.x;
    float d = cvt(ea[2*e]), c = cvt(ea[2*e + 1]);
    float v0 = d, v1 = c, v2 = d*d, v3 = c*c;
    #pragma unroll
    for (int o = 32; o > 0; o >>= 1) {
        v0 += __shfl_down(v0, o);
        v1 += __shfl_down(v1, o);
        v2 += __shfl_down(v2, o);
        v3 += __shfl_down(v3, o);
    }
    if ((threadIdx.x & 63) == 0) {
        unsafeAtomicAdd(&wsf[0], v0);
        unsafeAtomicAdd(&wsf[1], v1);
        unsafeAtomicAdd(&wsf[2], v2);
        unsafeAtomicAdd(&wsf[3], v3);
    }
}

__global__ __launch_bounds__(256) void k_stats(float* wsf, const void* ea)
{
    if (wsf[IDX_FLAG] > 0.5f) stats_body(wsf, (const bf16*)ea);
    else                      stats_body(wsf, (const float*)ea);
}

template<typename T>
__device__ __forceinline__ void init_body(float* wsf, const T* rain)
{
    int g = blockIdx.x * blockDim.x + threadIdx.x;
    if (g >= BN * NNODE) return;
    int b = g / NNODE, n = g % NNODE;
    wsf[OFF_XN + g] = cvt(rain[(b * HIST + (HIST - 1)) * NNODE + n]);
}

__global__ void k_init(float* wsf, const void* rain)
{
    if (wsf[IDX_FLAG] > 0.5f) init_body(wsf, (const bf16*)rain);
    else                      init_body(wsf, (const float*)rain);
}

__global__ __launch_bounds__(256) void k_csr_hist(int* wsi, const int* __restrict__ eidx)
{
    int e = blockIdx.x * 256 + threadIdx.x;
    atomicAdd(&wsi[RP_IN  + eidx[NEDGE + e]], 1);
    atomicAdd(&wsi[RP_OUT + eidx[e]],         1);
}

__global__ __launch_bounds__(256) void k_csr_scan(int* wsi)
{
    int* arr = (blockIdx.x == 0) ? (wsi + RP_IN)  : (wsi + RP_OUT);
    int* cur = (blockIdx.x == 0) ? (wsi + CUR_IN) : (wsi + CUR_OUT);
    __shared__ int tot[256], base[256];
    const int CH = 40;
    int tid = threadIdx.x, st = tid * CH;
    int loc[CH];
    int s = 0;
    #pragma unroll
    for (int i = 0; i < CH; i++) {
        int idx = st + i;
        int v = (idx < NNODE) ? arr[idx] : 0;
        loc[i] = s; s += v;
    }
    tot[tid] = s;
    __syncthreads();
    if (tid == 0) {
        int r = 0;
        for (int i = 0; i < 256; i++) { base[i] = r; r += tot[i]; }
        arr[NNODE] = r;
    }
    __syncthreads();
    int b = base[tid];
    #pragma unroll
    for (int i = 0; i < CH; i++) {
        int idx = st + i;
        if (idx < NNODE) { int v = b + loc[i]; arr[idx] = v; cur[idx] = v; }
    }
}

__global__ __launch_bounds__(256) void k_csr_fill(int* wsi, const int* __restrict__ eidx)
{
    int e = blockIdx.x * 256 + threadIdx.x;
    int src = eidx[e], tgt = eidx[NEDGE + e];
    int p = atomicAdd(&wsi[CUR_IN  + tgt], 1);
    wsi[PERM_IN + p] = e;
    wsi[IPOS_IN + e] = p;
    int q = atomicAdd(&wsi[CUR_OUT + src], 1);
    wsi[PERM_OUT + q] = e;
    wsi[IPOS_OUT + e] = q;
}

template<typename T>
__device__ __forceinline__ void edge_mlp(float* wsf, const int* eidx,
                                         const T* ea, const T* feature,
                                         int e, int b, int t, float f9[GOUT])
{
    const float* W = wsf + OFF_W;
    int src = eidx[e], tgt = eidx[NEDGE + e];

    const float invE = 1.0f / (float)NEDGE;
    float s0 = wsf[0], s1 = wsf[1], q0 = wsf[2], q1 = wsf[3];
    float m0 = s0 * invE, m1 = s1 * invE;
    float istd0 = rsqrtf(fmaxf((q0 - s0 * m0) * (1.0f / (NEDGE - 1)), 1e-20f));
    float istd1 = rsqrtf(fmaxf((q1 - s1 * m1) * (1.0f / (NEDGE - 1)), 1e-20f));

    float dist = cvt(ea[2*e]), cdir = cvt(ea[2*e + 1]);
    float ean0 = (dist - m0) * istd0, ean1 = (cdir - m1) * istd1;

    size_t frow = (size_t)(b * TSTEPS + HIST + t) * NNODE;
    const T* fS = feature + (frow + src) * FEAT;
    const T* fT = feature + (frow + tgt) * FEAT;
    float xnS = wsf[OFF_XN + b * NNODE + src];
    float xnT = wsf[OFF_XN + b * NNODE + tgt];

    float speed = cvt(fS[29]) * W[W_WSD + 0] + W[W_WM + 0];
    float direc = cvt(fS[30]) * W[W_WSD + 1] + W[W_WM + 1];
    float theta = fabsf(cdir - direc);
    float ew = fmaxf(3.0f * speed * cosf(theta * 22.5f) / dist, 0.0f);

    const float* We1 = W + W_WE1;
    float acc[EH];
    #pragma unroll
    for (int j = 0; j < EH; j++)
        acc[j] = W[W_BE1 + j] + xnS * We1[j] + xnT * We1[32*EH + j]
               + ean0 * We1[64*EH + j] + ean1 * We1[65*EH + j] + ew * We1[66*EH + j];
    for (int i = 0; i < FEAT; i++) {
        float v = cvt(fS[i]);
        const float* wr = We1 + (1 + i) * EH;
        #pragma unroll
        for (int j = 0; j < EH; j++) acc[j] += v * wr[j];
    }
    for (int i = 0; i < FEAT; i++) {
        float v = cvt(fT[i]);
        const float* wr = We1 + (33 + i) * EH;
        #pragma unroll
        for (int j = 0; j < EH; j++) acc[j] += v * wr[j];
    }
    #pragma unroll
    for (int j = 0; j < EH; j++) acc[j] = sigm(acc[j]);

    #pragma unroll
    for (int m = 0; m < GOUT; m++) f9[m] = 0.0f;
    const float* We2T = W + W_WE2T;
    const float* WnW  = W + W_WN;
    for (int k = 0; k < EOUT; k++) {
        float a = W[W_BE2 + k];
        const float* wr = We2T + k * EH;
        #pragma unroll
        for (int j = 0; j < EH; j++) a += acc[j] * wr[j];
        float ek = sigm(a);
        const float* wn = WnW + k * GOUT;
        #pragma unroll
        for (int m = 0; m < GOUT; m++) f9[m] += ek * wn[m];
    }
}

template<typename T>
__device__ __forceinline__ void edge_body(float* wsf, const int* eidx,
                                          const T* ea, const T* feature, int t)
{
    int e = blockIdx.x * 256 + threadIdx.x;
    int b = blockIdx.y;
    float f9[GOUT];
    edge_mlp(wsf, eidx, ea, feature, e, b, t, f9);
    int src = eidx[e], tgt = eidx[NEDGE + e];
    float* aggT = wsf + OFF_AGG + (size_t)(b * NNODE + tgt) * GOUT;
    float* aggS = wsf + OFF_AGG + (size_t)(b * NNODE + src) * GOUT;
    #pragma unroll
    for (int m = 0; m < GOUT; m++) {
        unsafeAtomicAdd(&aggT[m],  f9[m]);
        unsafeAtomicAdd(&aggS[m], -f9[m]);
    }
}

__global__ __launch_bounds__(256) void k_edge(float* wsf, const int* eidx,
                                              const void* ea, const void* feature, int t)
{
    if (wsf[IDX_FLAG] > 0.5f) edge_body(wsf, eidx, (const bf16*)ea, (const bf16*)feature, t);
    else                      edge_body(wsf, eidx, (const float*)ea, (const float*)feature, t);
}

template<typename T>
__device__ __forceinline__ void edge2_body(float* wsf, const int* eidx,
                                           const T* ea, const T* feature, int t)
{
    int e = blockIdx.x * 256 + threadIdx.x;
    int b = blockIdx.y;
    float f9[GOUT];
    edge_mlp(wsf, eidx, ea, feature, e, b, t, f9);
    float4* p = (float4*)(wsf + OFF_F9 + (size_t)(b * NEDGE + e) * 12);
    p[0] = make_float4(f9[0], f9[1], f9[2], f9[3]);
    p[1] = make_float4(f9[4], f9[5], f9[6], f9[7]);
    p[2] = make_float4(f9[8], 0.0f, 0.0f, 0.0f);
}

__global__ __launch_bounds__(256) void k_edge2(float* wsf, const int* eidx,
                                               const void* ea, const void* feature, int t)
{
    if (wsf[IDX_FLAG] > 0.5f) edge2_body(wsf, eidx, (const bf16*)ea, (const bf16*)feature, t);
    else                      edge2_body(wsf, eidx, (const float*)ea, (const float*)feature, t);
}

// ---- per-node precompute pS/pT + wind ----
template<typename T>
__device__ __forceinline__ void node_core(float* wsf, const T* srow, int b, int n)
{
    float x[32];
    x[0] = wsf[OFF_XN + b * NNODE + n];
    #pragma unroll
    for (int i = 0; i < FEAT; i++) x[1 + i] = cvt(srow[i]);

    const float* W = wsf + OFF_W;
    float acc[64];
    #pragma unroll
    for (int j = 0; j < 32; j++) acc[j] = W[W_BE1 + j];
    #pragma unroll
    for (int j = 0; j < 32; j++) acc[32 + j] = 0.0f;
    #pragma unroll
    for (int i = 0; i < 32; i++) {
        float v = x[i];
        const float* wS = W + W_WE1 + i * EH;
        const float* wT = W + W_WE1 + (32 + i) * EH;
        #pragma unroll
        for (int j = 0; j < 32; j++) { acc[j] += v * wS[j]; acc[32 + j] += v * wT[j]; }
    }

    float4* prow = (float4*)(wsf + OFF_PST + (size_t)(b * NNODE + n) * 64);
    #pragma unroll
    for (int jv = 0; jv < 16; jv++)
        prow[jv] = make_float4(acc[jv*4], acc[jv*4+1], acc[jv*4+2], acc[jv*4+3]);

    float speed = x[30] * W[W_WSD + 0] + W[W_WM + 0];
    float direc = x[31] * W[W_WSD + 1] + W[W_WM + 1];
    ((float2*)(wsf + OFF_WIND))[b * NNODE + n] = make_float2(speed, direc);
}

__global__ __launch_bounds__(256) void k_node(float* wsf, const void* feature, int t)
{
    __shared__ uint4 sfeat[992];                 // bf16 rows: 256*62B = 15872B
    int tid = threadIdx.x;
    int base = blockIdx.x * 256;
    int b = blockIdx.y;
    int n = base + tid;
    size_t frow = (size_t)(b * TSTEPS + HIST + t) * NNODE;
    if (wsf[IDX_FLAG] > 0.5f) {
        const bf16* feat = (const bf16*)feature;
        const int rowB = FEAT * 2;
        int nvalid = min(256, NNODE - base);
        int vbytes = nvalid * rowB;
        const uint4* gsrc = (const uint4*)((const char*)feat + (frow + base) * rowB);
        for (int c = tid; c * 16 < vbytes; c += 256) sfeat[c] = gsrc[c];
        __syncthreads();
        if (n >= NNODE) return;
        const bf16* srow = (const bf16*)((const char*)sfeat + (size_t)tid * rowB);
        node_core(wsf, srow, b, n);
    } else {
        if (n >= NNODE) return;
        const float* srow = (const float*)feature + (frow + n) * FEAT;
        node_core(wsf, srow, b, n);
    }
}

// ---- edge kernel: from pS/pT, bf16 f9 stores into CSR-ordered slots ----
template<typename T>
__device__ __forceinline__ void edge3_body(float* wsf, const int* wsi, const int* eidx,
                                           const T* ea, int t)
{
    int e = blockIdx.x * 256 + threadIdx.x;
    int b = blockIdx.y;
    const float* W = wsf + OFF_W;

    int src = eidx[e], tgt = eidx[NEDGE + e];
    int ipi = wsi[IPOS_IN + e], ipo = wsi[IPOS_OUT + e];

    const float invE = 1.0f / (float)NEDGE;
    float s0 = wsf[0], s1 = wsf[1], q0 = wsf[2], q1 = wsf[3];
    float m0 = s0 * invE, m1 = s1 * invE;
    float istd0 = rsqrtf(fmaxf((q0 - s0 * m0) * (1.0f / (NEDGE - 1)), 1e-20f));
    float istd1 = rsqrtf(fmaxf((q1 - s1 * m1) * (1.0f / (NEDGE - 1)), 1e-20f));

    float dist = cvt(ea[2*e]), cdir = cvt(ea[2*e + 1]);
    float ean0 = (dist - m0) * istd0, ean1 = (cdir - m1) * istd1;

    float2 wv = ((const float2*)(wsf + OFF_WIND))[b * NNODE + src];
    float theta = fabsf(cdir - wv.y);
    float ew = fmaxf(3.0f * wv.x * cosf(theta * 22.5f) / dist, 0.0f);

    const float4* ps4 = (const float4*)(wsf + OFF_PST + (size_t)(b * NNODE + src) * 64);
    const float4* pt4 = (const float4*)(wsf + OFF_PST + (size_t)(b * NNODE + tgt) * 64) + 8;

    float l1[EH];
    #pragma unroll
    for (int jv = 0; jv < 8; jv++) {
        float4 a = ps4[jv], c = pt4[jv];
        l1[jv*4+0] = a.x + c.x; l1[jv*4+1] = a.y + c.y;
        l1[jv*4+2] = a.z + c.z; l1[jv*4+3] = a.w + c.w;
    }
    const float* w64 = W + W_WE1 + 64*EH;
    const float* w65 = W + W_WE1 + 65*EH;
    const float* w66 = W + W_WE1 + 66*EH;
    #pragma unroll
    for (int j = 0; j < EH; j++)
        l1[j] = sigm(l1[j] + ean0 * w64[j] + ean1 * w65[j] + ew * w66[j]);

    float f9[GOUT];
    #pragma unroll
    for (int m = 0; m < GOUT; m++) f9[m] = 0.0f;
    const float* We2T = W + W_WE2T;
    const float* WnW  = W + W_WN;
    for (int k = 0; k < EOUT; k++) {
        float a = W[W_BE2 + k];
        const float* wr = We2T + k * EH;
        #pragma unroll
        for (int j = 0; j < EH; j++) a += l1[j] * wr[j];
        float ek = sigm(a);
        const float* wn = WnW + k * GOUT;
        #pragma unroll
        for (int m = 0; m < GOUT; m++) f9[m] += ek * wn[m];
    }

    unsigned u0 = f2b1(f9[0]) | (f2b1(f9[1]) << 16);
    unsigned u1 = f2b1(f9[2]) | (f2b1(f9[3]) << 16);
    unsigned u2 = f2b1(f9[4]) | (f2b1(f9[5]) << 16);
    unsigned u3 = f2b1(f9[6]) | (f2b1(f9[7]) << 16);
    unsigned u4 = f2b1(f9[8]);

    unsigned* pi = (unsigned*)(wsf + OFF_F9I) + ((size_t)b * NEDGE + ipi) * 8;
    ((uint4*)pi)[0] = make_uint4(u0, u1, u2, u3);
    pi[4] = u4;
    unsigned* po = (unsigned*)(wsf + OFF_F9O) + ((size_t)b * NEDGE + ipo) * 8;
    ((uint4*)po)[0] = make_uint4(u0, u1, u2, u3);
    po[4] = u4;
}

__global__ __launch_bounds__(256) void k_edge3(float* wsf, const int* eidx,
                                               const void* ea, int t)
{
    const int* wsi = (const int*)wsf;
    if (wsf[IDX_FLAG] > 0.5f) edge3_body(wsf, wsi, eidx, (const bf16*)ea, t);
    else                      edge3_body(wsf, wsi, eidx, (const float*)ea, t);
}

// ---- GRU core (R2/R3 fallback) ----
template<typename T, typename OT>
__device__ __forceinline__ void gru_core(float* wsf, const T* feature, OT* out, int t,
                                         int lane, int q, int g, int b, int n,
                                         const float agg[GOUT])
{
    __shared__ float lpx[4][64];
    const float* W = wsf + OFF_W;

    float xc[41];
    #pragma unroll
    for (int m = 0; m < GOUT; m++) xc[m] = sigm(agg[m] + W[W_BN + m]);
    xc[9] = wsf[OFF_XN + g];
    const T* fp = feature + ((size_t)(b * TSTEPS + HIST + t) * NNODE + n) * FEAT;
    #pragma unroll
    for (int i = 0; i < FEAT; i++) xc[10 + i] = cvt(fp[i]);

    float* hbuf = wsf + OFF_H + (size_t)g * HID;
    float h[HID];
    #pragma unroll
    for (int i = 0; i < HID; i++) h[i] = hbuf[i];
    float hmine[16];
    #pragma unroll
    for (int jj = 0; jj < 16; jj++) hmine[jj] = hbuf[(q << 4) + jj];

    __syncthreads();

    float px = 0.0f;
    for (int jj = 0; jj < 16; jj++) {
        int j = (q << 4) + jj;
        const float* wr = W + W_WIHT + j * 41;
        const float* wz = W + W_WIHT + (64 + j) * 41;
        const float* wg = W + W_WIHT + (128 + j) * 41;
        float ir = W[W_BIH + j], iz = W[W_BIH + 64 + j], ig = W[W_BIH + 128 + j];
        #pragma unroll
        for (int i = 0; i < 41; i++) {
            ir += xc[i] * wr[i]; iz += xc[i] * wz[i]; ig += xc[i] * wg[i];
        }
        const float* vr = W + W_WHHT + j * 64;
        const float* vz = W + W_WHHT + (64 + j) * 64;
        const float* vg = W + W_WHHT + (128 + j) * 64;
        float hr = W[W_BHH + j], hz = W[W_BHH + 64 + j], hg = W[W_BHH + 128 + j];
        #pragma unroll
        for (int i = 0; i < HID; i++) {
            hr += h[i] * vr[i]; hz += h[i] * vz[i]; hg += h[i] * vg[i];
        }
        float r  = sigm(ir + hr);
        float z  = sigm(iz + hz);
        float nn = tanhf(ig + r * hg);
        float hnew = (1.0f - z) * nn + z * hmine[jj];
        hbuf[j] = hnew;
        px += hnew * W[W_WOUT + j];
    }
    lpx[q][lane] = px;
    __syncthreads();
    if (q == 0) {
        float v = lpx[0][lane] + lpx[1][lane] + lpx[2][lane] + lpx[3][lane] + W[W_BOUT];
        wsf[OFF_XN + g] = v;
        out[((size_t)b * PRED + t) * NNODE + n] = (OT)v;
    }
}

template<typename T, typename OT>
__device__ __forceinline__ void gru_body(float* wsf, const T* feature, OT* out, int t)
{
    int lane = threadIdx.x & 63, q = threadIdx.x >> 6;
    int g = blockIdx.x * 64 + lane;
    int b = g / NNODE, n = g % NNODE;
    float agg[GOUT];
    const float* ap = wsf + OFF_AGG + (size_t)g * GOUT;
    #pragma unroll
    for (int m = 0; m < GOUT; m++) agg[m] = ap[m];
    gru_core(wsf, feature, out, t, lane, q, g, b, n, agg);
}

__global__ __launch_bounds__(256) void k_gru(float* wsf, const void* feature, void* out, int t)
{
    if (wsf[IDX_FLAG] > 0.5f) gru_body(wsf, (const bf16*)feature, (bf16*)out, t);
    else                      gru_body(wsf, (const float*)feature, (float*)out, t);
}

template<typename T, typename OT>
__device__ __forceinline__ void gru2_body(float* wsf, const int* wsi, const T* feature, OT* out, int t)
{
    int lane = threadIdx.x & 63, q = threadIdx.x >> 6;
    int g = blockIdx.x * 64 + lane;
    int b = g / NNODE, n = g % NNODE;

    const float* F9b = wsf + OFF_F9 + (size_t)b * NEDGE * 12;
    float agg[GOUT];
    #pragma unroll
    for (int m = 0; m < GOUT; m++) agg[m] = 0.0f;

    int i0 = wsi[RP_IN + n], i1 = wsi[RP_IN + n + 1];
    for (int i = i0; i < i1; i++) {
        int e = wsi[PERM_IN + i];
        const float4* p = (const float4*)(F9b + (size_t)e * 12);
        float4 a = p[0], c = p[1], d = p[2];
        agg[0] += a.x; agg[1] += a.y; agg[2] += a.z; agg[3] += a.w;
        agg[4] += c.x; agg[5] += c.y; agg[6] += c.z; agg[7] += c.w;
        agg[8] += d.x;
    }
    int o0 = wsi[RP_OUT + n], o1 = wsi[RP_OUT + n + 1];
    for (int i = o0; i < o1; i++) {
        int e = wsi[PERM_OUT + i];
        const float4* p = (const float4*)(F9b + (size_t)e * 12);
        float4 a = p[0], c = p[1], d = p[2];
        agg[0] -= a.x; agg[1] -= a.y; agg[2] -= a.z; agg[3] -= a.w;
        agg[4] -= c.x; agg[5] -= c.y; agg[6] -= c.z; agg[7] -= c.w;
        agg[8] -= d.x;
    }
    gru_core(wsf, feature, out, t, lane, q, g, b, n, agg);
}

__global__ __launch_bounds__(256) void k_gru2(float* wsf, const void* feature, void* out, int t)
{
    const int* wsi = (const int*)wsf;
    if (wsf[IDX_FLAG] > 0.5f) gru2_body(wsf, wsi, (const bf16*)feature, (bf16*)out, t);
    else                      gru2_body(wsf, wsi, (const float*)feature, (float*)out, t);
}

// ---- R5 GRU (fast2 fallback) ----
template<typename T, typename OT>
__device__ __forceinline__ void gru4_body(float* wsf, const int* wsi, const T* feature, OT* out, int t,
                                          float* xch, float* part, float* lpx)
{
    int tid = threadIdx.x;
    int lane = tid & 63, q = tid >> 6;
    int g = blockIdx.x * 64 + lane;
    int b = g / NNODE, n = g % NNODE;
    const float* W = wsf + OFF_W;

    float agg[GOUT];
    #pragma unroll
    for (int m = 0; m < GOUT; m++) agg[m] = 0.0f;
    {
        const unsigned* f9i = (const unsigned*)(wsf + OFF_F9I) + (size_t)b * NEDGE * 8;
        int i0 = wsi[RP_IN + n], i1 = wsi[RP_IN + n + 1];
        int ch = (i1 - i0 + 3) >> 2;
        int p0 = i0 + q * ch, p1 = min(p0 + ch, i1);
        for (int p = p0; p < p1; p++) {
            const unsigned* s = f9i + (size_t)p * 8;
            uint4 a = *(const uint4*)s; unsigned e8 = s[4];
            agg[0] += blo(a.x); agg[1] += bhi(a.x);
            agg[2] += blo(a.y); agg[3] += bhi(a.y);
            agg[4] += blo(a.z); agg[5] += bhi(a.z);
            agg[6] += blo(a.w); agg[7] += bhi(a.w);
            agg[8] += blo(e8);
        }
        const unsigned* f9o = (const unsigned*)(wsf + OFF_F9O) + (size_t)b * NEDGE * 8;
        int o0 = wsi[RP_OUT + n], o1 = wsi[RP_OUT + n + 1];
        ch = (o1 - o0 + 3) >> 2;
        p0 = o0 + q * ch; p1 = min(p0 + ch, o1);
        for (int p = p0; p < p1; p++) {
            const unsigned* s = f9o + (size_t)p * 8;
            uint4 a = *(const uint4*)s; unsigned e8 = s[4];
            agg[0] -= blo(a.x); agg[1] -= bhi(a.x);
            agg[2] -= blo(a.y); agg[3] -= bhi(a.y);
            agg[4] -= blo(a.z); agg[5] -= bhi(a.z);
            agg[6] -= blo(a.w); agg[7] -= bhi(a.w);
            agg[8] -= blo(e8);
        }
    }
    #pragma unroll
    for (int m = 0; m < GOUT; m++) part[(q * 64 + lane) * GOUT + m] = agg[m];

    float* Ht = wsf + OFF_H + (size_t)blockIdx.x * (64 * 64);
    #pragma unroll
    for (int k = 0; k < 16; k++) {
        int i = k * 4 + q;
        xch[(41 + i) * 64 + lane] = Ht[i * 64 + lane];
    }
    {
        size_t frow = (size_t)(b * TSTEPS + HIST + t) * NNODE;
        const T* fp = feature + (frow + n) * FEAT;
        for (int i = 10 + q; i < 41; i += 4)
            xch[i * 64 + lane] = cvt(fp[i - 10]);
    }
    __syncthreads();

    if (q == 0) {
        #pragma unroll
        for (int m = 0; m < GOUT; m++) {
            float s = part[(0 * 64 + lane) * GOUT + m] + part[(1 * 64 + lane) * GOUT + m]
                    + part[(2 * 64 + lane) * GOUT + m] + part[(3 * 64 + lane) * GOUT + m];
            xch[m * 64 + lane] = sigm(s + W[W_BN + m]);
        }
        xch[9 * 64 + lane] = wsf[OFF_XN + g];
    }
    __syncthreads();

    int jq = __builtin_amdgcn_readfirstlane(q);
    float px = 0.0f;
    #pragma unroll
    for (int jb = 0; jb < 4; jb++) {
        int j0 = jq * 16 + jb * 4;
        float ar[4], az[4], ag[4], ahg[4];
        #pragma unroll
        for (int u = 0; u < 4; u++) {
            ar[u]  = W[W_BIH + j0 + u] + W[W_BHH + j0 + u];
            az[u]  = W[W_BIH + 64 + j0 + u] + W[W_BHH + 64 + j0 + u];
            ag[u]  = W[W_BIH + 128 + j0 + u];
            ahg[u] = W[W_BHH + 128 + j0 + u];
        }
        for (int i = 0; i < 41; i++) {
            float v = xch[i * 64 + lane];
            #pragma unroll
            for (int u = 0; u < 4; u++) {
                ar[u] += v * W[W_WIHT + (j0 + u) * 41 + i];
                az[u] += v * W[W_WIHT + (64 + j0 + u) * 41 + i];
                ag[u] += v * W[W_WIHT + (128 + j0 + u) * 41 + i];
            }
        }
        for (int i = 0; i < 64; i++) {
            float v = xch[(41 + i) * 64 + lane];
            #pragma unroll
            for (int u = 0; u < 4; u++) {
                ar[u]  += v * W[W_WHHT + (j0 + u) * 64 + i];
                az[u]  += v * W[W_WHHT + (64 + j0 + u) * 64 + i];
                ahg[u] += v * W[W_WHHT + (128 + j0 + u) * 64 + i];
            }
        }
        #pragma unroll
        for (int u = 0; u < 4; u++) {
            float r  = sigm(ar[u]);
            float z  = sigm(az[u]);
            float nn = tanhf(ag[u] + r * ahg[u]);
            float hold = xch[(41 + j0 + u) * 64 + lane];
            float hnew = (1.0f - z) * nn + z * hold;
            Ht[(j0 + u) * 64 + lane] = hnew;
            px += hnew * W[W_WOUT + j0 + u];
        }
    }
    lpx[q * 64 + lane] = px;
    __syncthreads();
    if (q == 0) {
        float v = lpx[lane] + lpx[64 + lane] + lpx[128 + lane] + lpx[192 + lane] + W[W_BOUT];
        wsf[OFF_XN + g] = v;
        out[((size_t)b * PRED + t) * NNODE + n] = (OT)v;
    }
}

__global__ __launch_bounds__(256) void k_gru4(float* wsf, const void* feature, void* out, int t)
{
    __shared__ float xch[105 * 64];
    __shared__ float part[4 * 64 * GOUT];
    __shared__ float lpx[4 * 64];
    const int* wsi = (const int*)wsf;
    if (wsf[IDX_FLAG] > 0.5f) gru4_body(wsf, wsi, (const bf16*)feature, (bf16*)out, t, xch, part, lpx);
    else                      gru4_body(wsf, wsi, (const float*)feature, (float*)out, t, xch, part, lpx);
}

// ---- R6 GRU: MFMA gates ----
// xh[node][k] bf16, row stride 136 (k: 0..63 h, 64..72 gnn, 73 xn, 74..104 feat, 105..135 zero)
// H layout: Ht[node][i] f32, block-local (4096 floats per block)
#define XHS 136
template<typename T, typename OT>
__device__ __forceinline__ void gru5_body(float* wsf, const int* wsi, const T* feature, OT* out, int t,
                                          unsigned short* xh, float* part)
{
    int tid = threadIdx.x;
    int lane = tid & 63, q = tid >> 6;
    int g = blockIdx.x * 64 + lane;
    int b = g / NNODE, n = g % NNODE;
    const float* W = wsf + OFF_W;
    float* Ht = wsf + OFF_H + (size_t)blockIdx.x * 4096;

    // ---- gather (node = lane; wave q takes quarter of each list) ----
    float agg[GOUT];
    #pragma unroll
    for (int m = 0; m < GOUT; m++) agg[m] = 0.0f;
    {
        const unsigned* f9i = (const unsigned*)(wsf + OFF_F9I) + (size_t)b * NEDGE * 8;
        int i0 = wsi[RP_IN + n], i1 = wsi[RP_IN + n + 1];
        int ch = (i1 - i0 + 3) >> 2;
        int p0 = i0 + q * ch, p1 = min(p0 + ch, i1);
        for (int p = p0; p < p1; p++) {
            const unsigned* s = f9i + (size_t)p * 8;
            uint4 a = *(const uint4*)s; unsigned e8 = s[4];
            agg[0] += blo(a.x); agg[1] += bhi(a.x);
            agg[2] += blo(a.y); agg[3] += bhi(a.y);
            agg[4] += blo(a.z); agg[5] += bhi(a.z);
            agg[6] += blo(a.w); agg[7] += bhi(a.w);
            agg[8] += blo(e8);
        }
        const unsigned* f9o = (const unsigned*)(wsf + OFF_F9O) + (size_t)b * NEDGE * 8;
        int o0 = wsi[RP_OUT + n], o1 = wsi[RP_OUT + n + 1];
        ch = (o1 - o0 + 3) >> 2;
        p0 = o0 + q * ch; p1 = min(p0 + ch, o1);
        for (int p = p0; p < p1; p++) {
            const unsigned* s = f9o + (size_t)p * 8;
            uint4 a = *(const uint4*)s; unsigned e8 = s[4];
            agg[0] -= blo(a.x); agg[1] -= bhi(a.x);
            agg[2] -= blo(a.y); agg[3] -= bhi(a.y);
            agg[4] -= blo(a.z); agg[5] -= bhi(a.z);
            agg[6] -= blo(a.w); agg[7] -= bhi(a.w);
            agg[8] -= blo(e8);
        }
    }
    #pragma unroll
    for (int m = 0; m < GOUT; m++) part[(q * 64 + lane) * GOUT + m] = agg[m];

    // ---- stage h (f32 -> bf16), coalesced: thread t = node (tid>>2), chunk (tid&3) of 16 ----
    {
        int nd = tid >> 2, c = tid & 3;
        const float4* hp4 = (const float4*)(Ht + nd * 64 + c * 16);
        unsigned o[8];
        #pragma unroll
        for (int v = 0; v < 4; v++) {
            float4 f = hp4[v];
            o[2*v]   = f2b1(f.x) | (f2b1(f.y) << 16);
            o[2*v+1] = f2b1(f.z) | (f2b1(f.w) << 16);
        }
        unsigned* dst = (unsigned*)&xh[nd * XHS + c * 16];
        #pragma unroll
        for (int v = 0; v < 8; v++) dst[v] = o[v];
    }
    // ---- stage feature (node = lane), zero-pad ----
    {
        size_t frow = (size_t)(b * TSTEPS + HIST + t) * NNODE;
        const T* fp = feature + (frow + n) * FEAT;
        for (int ix = q; ix < FEAT; ix += 4)
            xh[lane * XHS + 74 + ix] = (unsigned short)f2b1(cvt(fp[ix]));
        for (int kx = 105 + q; kx < XHS; kx += 4)
            xh[lane * XHS + kx] = 0;
    }
    __syncthreads();

    if (q == 0) {
        #pragma unroll
        for (int m = 0; m < GOUT; m++) {
            float s = part[lane * GOUT + m] + part[(64 + lane) * GOUT + m]
                    + part[(128 + lane) * GOUT + m] + part[(192 + lane) * GOUT + m];
            xh[lane * XHS + 64 + m] = (unsigned short)f2b1(sigm(s + W[W_BN + m]));
        }
        xh[lane * XHS + 73] = (unsigned short)f2b1(wsf[OFF_XN + g]);
    }
    __syncthreads();

    // ---- MFMA: wave q = M-tile q (nodes q*16..+16); N=256 (r|z|ig|hg), K=128 ----
    int col = lane & 15, quad = lane >> 4;
    bf16x8 A[4];
    #pragma unroll
    for (int Kt = 0; Kt < 4; Kt++)
        A[Kt] = *(const bf16x8*)&xh[(q * 16 + col) * XHS + Kt * 32 + quad * 8];

    const bf16x8* Bf = (const bf16x8*)(wsf + WFRAG);
    f32x4 C[16];
    #pragma unroll
    for (int Nt = 0; Nt < 16; Nt++) C[Nt] = (f32x4){0.f, 0.f, 0.f, 0.f};
    #pragma unroll 4
    for (int Nt = 0; Nt < 16; Nt++) {
        const bf16x8* bp = Bf + (size_t)Nt * 256 + lane;
        #pragma unroll
        for (int Kt = 0; Kt < 4; Kt++)
            C[Nt] = __builtin_amdgcn_mfma_f32_16x16x32_bf16(A[Kt], bp[Kt * 64], C[Nt], 0, 0, 0);
    }

    // ---- epilogue: lane owns (m = q*16+quad*4+reg, j = nt*16+col) ----
    float pxm[4] = {0.f, 0.f, 0.f, 0.f};
    #pragma unroll
    for (int nt = 0; nt < 4; nt++) {
        int j = nt * 16 + col;
        float br = W[W_BIH + j] + W[W_BHH + j];
        float bz = W[W_BIH + 64 + j] + W[W_BHH + 64 + j];
        float bg = W[W_BIH + 128 + j];
        float bh = W[W_BHH + 128 + j];
        float wo = W[W_WOUT + j];
        #pragma unroll
        for (int reg = 0; reg < 4; reg++) {
            int m64 = q * 16 + quad * 4 + reg;
            float r  = sigm(C[nt][reg] + br);
            float z  = sigm(C[nt + 4][reg] + bz);
            float nn = tanhf(C[nt + 8][reg] + bg + r * (C[nt + 12][reg] + bh));
            float hold = Ht[m64 * 64 + j];
            float hnew = (1.0f - z) * nn + z * hold;
            Ht[m64 * 64 + j] = hnew;
            pxm[reg] += hnew * wo;
        }
    }
    // reduce over col (low 4 lane bits)
    #pragma unroll
    for (int off = 1; off < 16; off <<= 1) {
        #pragma unroll
        for (int reg = 0; reg < 4; reg++)
            pxm[reg] += __shfl_xor(pxm[reg], off);
    }
    if (col == 0) {
        #pragma unroll
        for (int reg = 0; reg < 4; reg++) {
            int m64 = q * 16 + quad * 4 + reg;
            int g2 = blockIdx.x * 64 + m64;
            int b2 = g2 / NNODE, n2 = g2 % NNODE;
            float v = pxm[reg] + W[W_BOUT];
            wsf[OFF_XN + g2] = v;
            out[((size_t)b2 * PRED + t) * NNODE + n2] = (OT)v;
        }
    }
}

__global__ __launch_bounds__(256) void k_gru5(float* wsf, const void* feature, void* out, int t)
{
    __shared__ unsigned short xh[64 * XHS];   // 17408 B
    __shared__ float part[4 * 64 * GOUT];     // 9216 B
    const int* wsi = (const int*)wsf;
    if (wsf[IDX_FLAG] > 0.5f) gru5_body(wsf, wsi, (const bf16*)feature, (bf16*)out, t, xh, part);
    else                      gru5_body(wsf, wsi, (const float*)feature, (float*)out, t, xh, part);
}

extern "C" void kernel_launch(void* const* d_in, const int* in_sizes, int n_in,
                              void* d_out, int out_size, void* d_ws, size_t ws_size,
                              hipStream_t stream)
{
    float* wsf = (float*)d_ws;
    int*   wsi = (int*)d_ws;
    const void* rain    = d_in[0];
    const void* feature = d_in[1];
    const int*  eidx    = (const int*)d_in[2];
    const void* ea      = d_in[3];
    const void* wm      = d_in[4];
    const void* wsd     = d_in[5];

    bool fast3 = (ws_size >= NEW3_WS_BYTES);
    bool fast2 = (ws_size >= NEW_WS_BYTES);
    bool fast  = (ws_size >= FAST_WS_BYTES);

    hipMemsetAsync(wsf, 0, 16 * sizeof(float), stream);
    hipMemsetAsync(wsf + OFF_H, 0, (size_t)BN * NNODE * HID * sizeof(float), stream);

    k_sniff<<<1, 64, 0, stream>>>(wsf, ea);
    k_weights<<<(W_TOTAL + 255) / 256, 256, 0, stream>>>(wsf,
        d_in[6], d_in[7], d_in[8], d_in[9], d_in[10], d_in[11], d_in[12],
        d_in[13], d_in[14], d_in[15], d_in[16], d_in[17], wm, wsd);
    k_stats<<<NEDGE / 256, 256, 0, stream>>>(wsf, ea);
    k_init<<<(BN * NNODE + 255) / 256, 256, 0, stream>>>(wsf, rain);

    if (fast3 || fast2 || fast) {
        hipMemsetAsync(wsi + RP_IN, 0, 20032 * sizeof(int), stream);
        k_csr_hist<<<NEDGE / 256, 256, 0, stream>>>(wsi, eidx);
        k_csr_scan<<<2, 256, 0, stream>>>(wsi);
        k_csr_fill<<<NEDGE / 256, 256, 0, stream>>>(wsi, eidx);
    }

    if (fast3) {
        k_wfrag<<<128, 256, 0, stream>>>(wsf);
        for (int t = 0; t < PRED; t++) {
            dim3 gn((NNODE + 255) / 256, BN);
            k_node<<<gn, 256, 0, stream>>>(wsf, feature, t);
            dim3 ge(NEDGE / 256, BN);
            k_edge3<<<ge, 256, 0, stream>>>(wsf, eidx, ea, t);
            k_gru5<<<(BN * NNODE) / 64, 256, 0, stream>>>(wsf, feature, d_out, t);
        }
    } else if (fast2) {
        for (int t = 0; t < PRED; t++) {
            dim3 gn((NNODE + 255) / 256, BN);
            k_node<<<gn, 256, 0, stream>>>(wsf, feature, t);
            dim3 ge(NEDGE / 256, BN);
            k_edge3<<<ge, 256, 0, stream>>>(wsf, eidx, ea, t);
            k_gru4<<<(BN * NNODE) / 64, 256, 0, stream>>>(wsf, feature, d_out, t);
        }
    } else if (fast) {
        for (int t = 0; t < PRED; t++) {
            dim3 ge(NEDGE / 256, BN);
            k_edge2<<<ge, 256, 0, stream>>>(wsf, eidx, ea, feature, t);
            k_gru2<<<(BN * NNODE) / 64, 256, 0, stream>>>(wsf, feature, d_out, t);
        }
    } else {
        for (int t = 0; t < PRED; t++) {
            hipMemsetAsync(wsf + OFF_AGG, 0, (size_t)BN * NNODE * GOUT * sizeof(float), stream);
            dim3 ge(NEDGE / 256, BN);
            k_edge<<<ge, 256, 0, stream>>>(wsf, eidx, ea, feature, t);
            k_gru<<<(BN * NNODE) / 64, 256, 0, stream>>>(wsf, feature, d_out, t);
        }
    }
}